// Round 7
// baseline (658.341 us; speedup 1.0000x reference)
//
#include <hip/hip_runtime.h>
#include <hip/hip_bf16.h>
#include <math.h>

constexpr int kB    = 64;
constexpr int kN    = 36;
constexpr int kBN   = kB * kN;   // 2304
constexpr int kD    = 2048;
constexpr int kDatt = 512;
constexpr int kPairs = kN * kN;  // 1296

using bf16x8 = __attribute__((ext_vector_type(8))) short;
using f32x4  = __attribute__((ext_vector_type(4))) float;

typedef unsigned int u32;
typedef __attribute__((address_space(3))) u32 lds_u32;
typedef const __attribute__((address_space(1))) u32 glb_u32;

__device__ inline unsigned short f2bf(float f) {
    union { float f; unsigned u; } v; v.f = f;
    unsigned r = v.u + 0x7FFFu + ((v.u >> 16) & 1u);   // RNE
    return (unsigned short)(r >> 16);
}

// ---------------------------------------------------------------------------
// kcvt: f32 -> bf16 elementwise
// ---------------------------------------------------------------------------
__global__ __launch_bounds__(256)
void kcvt(const float* __restrict__ x, unsigned short* __restrict__ y, int n4)
{
    int i = blockIdx.x * 256 + threadIdx.x;
    if (i < n4) {
        float4 v = ((const float4*)x)[i];
        ushort4 o = {f2bf(v.x), f2bf(v.y), f2bf(v.z), f2bf(v.w)};
        ((ushort4*)y)[i] = o;
    }
}

// ---------------------------------------------------------------------------
// ktrp: W[kD][nt] f32 -> WT[nt][kD] bf16 (transpose + convert)
// ---------------------------------------------------------------------------
__global__ __launch_bounds__(256)
void ktrp(const float* __restrict__ W, unsigned short* __restrict__ WT, int nt)
{
    __shared__ float T[64][65];
    const int k0 = blockIdx.x * 64;
    const int n0 = blockIdx.y * 64;
    const int c = threadIdx.x & 63, r0 = threadIdx.x >> 6;
    #pragma unroll
    for (int rr = 0; rr < 64; rr += 4)
        T[r0 + rr][c] = W[(size_t)(k0 + r0 + rr) * nt + n0 + c];
    __syncthreads();
    #pragma unroll
    for (int rr = 0; rr < 64; rr += 4)
        WT[(size_t)(n0 + r0 + rr) * kD + k0 + c] = f2bf(T[c][r0 + rr]);
}

// ---------------------------------------------------------------------------
// krepack_w0: W0T[col][k] bf16 -> W0s, k4-tile-major with the conflict-free
// granule permutation baked in (see k4 header).
// ---------------------------------------------------------------------------
__global__ __launch_bounds__(64)
void krepack_w0(const unsigned short* __restrict__ W0T, unsigned short* __restrict__ W0s)
{
    const int kb    = blockIdx.x;   // 0..63  : K-block (32 k's)
    const int chunk = blockIdx.y;   // 0..31  : 16-row chunk
    const int g     = threadIdx.x;  // 0..63  : granule
    const int row = chunk * 16 + (g & 7) + ((g >> 5) << 3);
    const int cg8 = ((g >> 3) & 3) * 8;
    const uint4 v = *(const uint4*)&W0T[(size_t)row * kD + kb * 32 + cg8];
    *(uint4*)&W0s[(size_t)kb * 16384 + chunk * 512 + g * 8] = v;
}

// ---------------------------------------------------------------------------
// kgbox (parallel): Gpart[kc][uv][c] = sum_{k in chunk kc}
//   Wba[u,k]*Wbb[v,k]*W0[k,c].  Grid (8 c-tiles, 16 k-chunks) x 256 thr.
// ---------------------------------------------------------------------------
__global__ __launch_bounds__(256)
void kgbox(const float* __restrict__ Wba, const float* __restrict__ Wbb,
           const float* __restrict__ W0, float* __restrict__ Gpart)
{
    __shared__ float red[4][64][17];
    const int ct = blockIdx.x;            // 0..7  : 64-col tile
    const int kc = blockIdx.y;            // 0..15 : 128-k chunk
    const int cl = threadIdx.x & 63;
    const int kq = threadIdx.x >> 6;      // 0..3
    const int c  = ct * 64 + cl;

    float acc[16];
    #pragma unroll
    for (int t = 0; t < 16; ++t) acc[t] = 0.f;

    const int kbase = kc * 128 + kq * 32;
    for (int kk = 0; kk < 32; ++kk) {
        int k = kbase + kk;
        float w0 = W0[(size_t)k * kDatt + c];
        float a0 = Wba[k], a1 = Wba[kD + k], a2 = Wba[2 * kD + k], a3 = Wba[3 * kD + k];
        float b0 = Wbb[k] * w0, b1 = Wbb[kD + k] * w0,
              b2 = Wbb[2 * kD + k] * w0, b3 = Wbb[3 * kD + k] * w0;
        acc[0]  = fmaf(a0, b0, acc[0]);  acc[1]  = fmaf(a0, b1, acc[1]);
        acc[2]  = fmaf(a0, b2, acc[2]);  acc[3]  = fmaf(a0, b3, acc[3]);
        acc[4]  = fmaf(a1, b0, acc[4]);  acc[5]  = fmaf(a1, b1, acc[5]);
        acc[6]  = fmaf(a1, b2, acc[6]);  acc[7]  = fmaf(a1, b3, acc[7]);
        acc[8]  = fmaf(a2, b0, acc[8]);  acc[9]  = fmaf(a2, b1, acc[9]);
        acc[10] = fmaf(a2, b2, acc[10]); acc[11] = fmaf(a2, b3, acc[11]);
        acc[12] = fmaf(a3, b0, acc[12]); acc[13] = fmaf(a3, b1, acc[13]);
        acc[14] = fmaf(a3, b2, acc[14]); acc[15] = fmaf(a3, b3, acc[15]);
    }
    #pragma unroll
    for (int t = 0; t < 16; ++t) red[kq][cl][t] = acc[t];
    __syncthreads();
    #pragma unroll
    for (int t = 0; t < 4; ++t) {
        int s = threadIdx.x + t * 256;    // 0..1023 : cc*16 + uv
        int cc = s >> 4, uv = s & 15;
        float v = red[0][cc][uv] + red[1][cc][uv] + red[2][cc][uv] + red[3][cc][uv];
        Gpart[((size_t)kc * 16 + uv) * kDatt + ct * 64 + cc] = v;
    }
}

// ---------------------------------------------------------------------------
// krepack_g: sum the 16 k-chunk partials (f32) -> W0s K-block 64 (bf16,
// permuted layout, k_local = uv for uv<16, zero for 16..31).
// ---------------------------------------------------------------------------
__global__ __launch_bounds__(64)
void krepack_g(const float* __restrict__ Gpart, unsigned short* __restrict__ W0s)
{
    const int chunk = blockIdx.x;   // 0..31 : 16-col chunk
    const int g     = threadIdx.x;  // 0..63 : granule
    const int col = chunk * 16 + (g & 7) + ((g >> 5) << 3);
    const int kg  = (g >> 3) & 3;
    unsigned short o[8];
    #pragma unroll
    for (int e = 0; e < 8; ++e) {
        int kl = kg * 8 + e;
        if (kl < 16) {
            float s = 0.f;
            #pragma unroll
            for (int kc = 0; kc < 16; ++kc)
                s += Gpart[((size_t)kc * 16 + kl) * kDatt + col];
            o[e] = f2bf(s);
        } else o[e] = 0;
    }
    *(uint4*)&W0s[(size_t)64 * 16384 + chunk * 512 + g * 8] = *(uint4*)o;
}

// ---------------------------------------------------------------------------
// Staging helpers for k1/k2: Rx32 bf16 tiles via global_load_lds width=16.
// ---------------------------------------------------------------------------
__device__ inline void stage128(const unsigned short* __restrict__ g,
                                int grow0, int k0,
                                unsigned short* lds, int w, int lane)
{
    const int sr = lane >> 2, sc = (lane & 3) * 8;
    #pragma unroll
    for (int t = 0; t < 2; ++t) {
        int r = w * 32 + t * 16;
        const unsigned short* gp = g + (size_t)(grow0 + r + sr) * kD + k0 + sc;
        __builtin_amdgcn_global_load_lds((glb_u32*)gp, (lds_u32*)(lds + r * 32), 16, 0, 0);
    }
}
__device__ inline void stage64(const unsigned short* __restrict__ g,
                               int grow0, int k0,
                               unsigned short* lds, int w, int lane)
{
    const int sr = lane >> 2, sc = (lane & 3) * 8;
    int r = w * 16;
    const unsigned short* gp = g + (size_t)(grow0 + r + sr) * kD + k0 + sc;
    __builtin_amdgcn_global_load_lds((glb_u32*)gp, (lds_u32*)(lds + r * 32), 16, 0, 0);
}

// ---------------------------------------------------------------------------
// K1 (MFMA dual): fused_bf16 = bf16((Qb @ WqT') .* (Ob @ WoT')), 128x64 tile
// ---------------------------------------------------------------------------
__global__ __launch_bounds__(256, 2)
void k1_dual_mfma(const unsigned short* __restrict__ Qb,
                  const unsigned short* __restrict__ WqT,
                  const unsigned short* __restrict__ Ob,
                  const unsigned short* __restrict__ WoT,
                  unsigned short* __restrict__ fusedb)
{
    __shared__ __align__(16) unsigned short As1[128][32];
    __shared__ __align__(16) unsigned short As2[128][32];
    __shared__ __align__(16) unsigned short Bs1[64][32];
    __shared__ __align__(16) unsigned short Bs2[64][32];

    const int tid = threadIdx.x;
    const int lane = tid & 63;
    const int w = tid >> 6;
    const int wm = w >> 1, wn = w & 1;
    const int row0 = blockIdx.y * 128;
    const int col0 = blockIdx.x * 64;

    f32x4 acc1[4][2], acc2[4][2];
    #pragma unroll
    for (int mt = 0; mt < 4; ++mt)
        #pragma unroll
        for (int nt = 0; nt < 2; ++nt) { acc1[mt][nt] = (f32x4)(0.f); acc2[mt][nt] = (f32x4)(0.f); }

    const int fr = lane & 15, ko = (lane >> 4) * 8;

    for (int k0 = 0; k0 < kD; k0 += 32) {
        stage128(Qb,  row0, k0, &As1[0][0], w, lane);
        stage128(Ob,  row0, k0, &As2[0][0], w, lane);
        stage64 (WqT, col0, k0, &Bs1[0][0], w, lane);
        stage64 (WoT, col0, k0, &Bs2[0][0], w, lane);
        __syncthreads();

        bf16x8 a1[4], a2[4];
        #pragma unroll
        for (int mt = 0; mt < 4; ++mt) {
            a1[mt] = *(bf16x8*)&As1[wm * 64 + mt * 16 + fr][ko];
            a2[mt] = *(bf16x8*)&As2[wm * 64 + mt * 16 + fr][ko];
        }
        #pragma unroll
        for (int nt = 0; nt < 2; ++nt) {
            bf16x8 b1 = *(bf16x8*)&Bs1[wn * 32 + nt * 16 + fr][ko];
            bf16x8 b2 = *(bf16x8*)&Bs2[wn * 32 + nt * 16 + fr][ko];
            #pragma unroll
            for (int mt = 0; mt < 4; ++mt) {
                acc1[mt][nt] = __builtin_amdgcn_mfma_f32_16x16x32_bf16(a1[mt], b1, acc1[mt][nt], 0, 0, 0);
                acc2[mt][nt] = __builtin_amdgcn_mfma_f32_16x16x32_bf16(a2[mt], b2, acc2[mt][nt], 0, 0, 0);
            }
        }
        __syncthreads();
    }

    const int fq = lane >> 4;
    #pragma unroll
    for (int mt = 0; mt < 4; ++mt)
        #pragma unroll
        for (int nt = 0; nt < 2; ++nt) {
            int row = row0 + wm * 64 + mt * 16 + fq * 4;
            int col = col0 + wn * 32 + nt * 16 + fr;
            #pragma unroll
            for (int reg = 0; reg < 4; ++reg) {
                float v = acc1[mt][nt][reg] * acc2[mt][nt][reg];
                fusedb[(size_t)(row + reg) * kD + col] = f2bf(v);
            }
        }
}

// ---------------------------------------------------------------------------
// K2 (MFMA dual-B): ra = Fb @ WfaT', rb = Fb @ WfbT', 128x64 tile
// ---------------------------------------------------------------------------
__global__ __launch_bounds__(256, 2)
void k2_dual_mfma(const unsigned short* __restrict__ Fb,
                  const unsigned short* __restrict__ WfaT,
                  const unsigned short* __restrict__ WfbT,
                  float* __restrict__ ra, float* __restrict__ rb)
{
    __shared__ __align__(16) unsigned short As [128][32];
    __shared__ __align__(16) unsigned short Bs1[64][32];
    __shared__ __align__(16) unsigned short Bs2[64][32];

    const int tid = threadIdx.x;
    const int lane = tid & 63;
    const int w = tid >> 6;
    const int wm = w >> 1, wn = w & 1;
    const int row0 = blockIdx.y * 128;
    const int col0 = blockIdx.x * 64;

    f32x4 acc1[4][2], acc2[4][2];
    #pragma unroll
    for (int mt = 0; mt < 4; ++mt)
        #pragma unroll
        for (int nt = 0; nt < 2; ++nt) { acc1[mt][nt] = (f32x4)(0.f); acc2[mt][nt] = (f32x4)(0.f); }

    const int fr = lane & 15, ko = (lane >> 4) * 8;

    for (int k0 = 0; k0 < kD; k0 += 32) {
        stage128(Fb,   row0, k0, &As [0][0], w, lane);
        stage64 (WfaT, col0, k0, &Bs1[0][0], w, lane);
        stage64 (WfbT, col0, k0, &Bs2[0][0], w, lane);
        __syncthreads();

        bf16x8 a[4];
        #pragma unroll
        for (int mt = 0; mt < 4; ++mt)
            a[mt] = *(bf16x8*)&As[wm * 64 + mt * 16 + fr][ko];
        #pragma unroll
        for (int nt = 0; nt < 2; ++nt) {
            bf16x8 b1 = *(bf16x8*)&Bs1[wn * 32 + nt * 16 + fr][ko];
            bf16x8 b2 = *(bf16x8*)&Bs2[wn * 32 + nt * 16 + fr][ko];
            #pragma unroll
            for (int mt = 0; mt < 4; ++mt) {
                acc1[mt][nt] = __builtin_amdgcn_mfma_f32_16x16x32_bf16(a[mt], b1, acc1[mt][nt], 0, 0, 0);
                acc2[mt][nt] = __builtin_amdgcn_mfma_f32_16x16x32_bf16(a[mt], b2, acc2[mt][nt], 0, 0, 0);
            }
        }
        __syncthreads();
    }

    const int fq = lane >> 4;
    #pragma unroll
    for (int mt = 0; mt < 4; ++mt)
        #pragma unroll
        for (int nt = 0; nt < 2; ++nt) {
            int row = row0 + wm * 64 + mt * 16 + fq * 4;
            int col = col0 + wn * 32 + nt * 16 + fr;
            #pragma unroll
            for (int reg = 0; reg < 4; ++reg) {
                size_t o = (size_t)(row + reg) * kD + col;
                ra[o] = acc1[mt][nt][reg];
                rb[o] = acc2[mt][nt][reg];
            }
        }
}

// ---------------------------------------------------------------------------
// K4 v10: step-internal reorder. v9 analysis: LDS port floor ~2100 cyc/step
// but measured ~3900 -- ~1500 cyc of latency gaps because REL_GEN (which is
// independent of this step's MFMA: writes RelS[nxt]/reads Stg[nxt] vs MFMA
// reading RelS[cur]/Bs[cur]) sat AFTER the MFMA cluster. New order per step:
//   barrier -> STAGE_LOAD issue -> ISSUE_B -> af reads -> REL_GEN(nxt)
//   -> setprio(1) MFMA setprio(0) -> STAGE_WRITE(cur)
// af reads issue ~10 LDS-ops before first MFMA use; REL_GEN VALU fills the
// latency window; setprio favors the MFMA cluster (waves now role-diverse);
// STAGE_WRITE keeps its vmcnt wait after MFMA (load issued this step).
// All cross-step hazards identical to v8/v9. bfv reads stay inline in the
// MFMA loop (hoisting all 4 would add 32 live VGPRs past the 128/wave
// 4-wave/SIMD cliff; current 64 arch + 64 acc = exactly 128).
// ---------------------------------------------------------------------------
__global__ __launch_bounds__(1024)
void k4_scores_mfma(const float* __restrict__ ra, const float* __restrict__ rb,
                    const float* __restrict__ box,
                    const unsigned short* __restrict__ W0s,
                    const float* __restrict__ b0, const float* __restrict__ W1,
                    float* __restrict__ scores)
{
    __shared__ __align__(16) unsigned short Bs[2][512 * 32];  // 64 KB
    __shared__ __align__(16) unsigned short RelS[2][128][40]; // 20 KB
    __shared__ __align__(16) float4 Stg4[2][378];             // 12 KB : 42 rows x (8+1) f4
    __shared__ float scoreS[128];

    const int tid  = threadIdx.x;
    const int lane = tid & 63;
    const int w    = tid >> 6;        // 0..15
    const int wm   = w >> 3;          // 0..1 : M-half (64 rows)
    const int wn   = w & 7;           // 0..7 : N-eighth (64 cols)

    // XCD-chunked swizzle: 704 = 8 XCDs x 88; same-b tiles stay on one XCD
    const int work = (blockIdx.x & 7) * 88 + (blockIdx.x >> 3);
    const int b    = work / 11;
    const int tile = work - b * 11;   // 0..10 (tile 10: 16 valid rows)
    const int p0   = tile * 128;      // first pair index within b
    const int i0   = p0 / kN;

    const float* raB  = ra  + (size_t)b * kN * kD;
    const float* rbB  = rb  + (size_t)b * kN * kD;
    const float* boxB = box + (size_t)b * kN * 4;

    // ---- stage slots: 336 = 42 rows x 8 f4 (rows 0..5 = i-rows of ra,
    //      rows 6..41 = j-rows of rb); Stg row stride 9 f4 (pad)
    const bool hasStage = (tid < 336);
    const float* sptr;
    int sdst;
    {
        int s = hasStage ? tid : 335;
        int row = s >> 3, q = s & 7;
        int grow; const float* base;
        if (row < 6) {
            int il = (row < 5) ? row : 4;
            grow = i0 + il; if (grow > kN - 1) grow = kN - 1;
            base = raB;
        } else {
            grow = row - 6;
            base = rbB;
        }
        sptr = base + (size_t)grow * kD + q * 4;
        sdst = row * 9 + q;
    }

    // ---- Rel-gen slot: 1024 = 128 rows x 8 col-groups; one per thread
    int rowA, cgA, ilA, iA, jA;
    {
        rowA = tid >> 3; cgA = tid & 7;
        int p = p0 + rowA; if (p >= kPairs) p = kPairs - 1;
        iA  = p / kN;
        jA  = p - iA * kN;
        ilA = iA - i0;
    }

    const int fr = lane & 15, fq = lane >> 4;
    const int bco = ((fr & 7) << 3) + ((fr >> 3) << 8) + (fq << 6);

    f32x4 acc[4][4];
    #pragma unroll
    for (int mt = 0; mt < 4; ++mt)
        #pragma unroll
        for (int nt = 0; nt < 4; ++nt)
            acc[mt][nt] = (f32x4)(0.f);

    if (tid < 128) scoreS[tid] = 0.f;

    float4 sreg0;

    #define ISSUE_B(k0_, buf_)                                                   \
        _Pragma("unroll")                                                        \
        for (int t = 0; t < 2; ++t) {                                            \
            int chunk = w * 2 + t;                                               \
            const unsigned short* gp = W0s + (size_t)((k0_) >> 5) * 16384        \
                                       + chunk * 512 + lane * 8;                 \
            __builtin_amdgcn_global_load_lds((glb_u32*)gp,                       \
                (lds_u32*)&Bs[buf_][chunk * 512], 16, 0, 0);                     \
        }

    #define STAGE_LOAD(k0_) {                                                    \
            if (hasStage) sreg0 = *(const float4*)(sptr + (k0_));                \
        }

    #define STAGE_WRITE(buf_) {                                                  \
            if (hasStage) Stg4[buf_][sdst] = sreg0;                              \
        }

    #define REL_GEN(buf_) {                                                      \
            float4 va = Stg4[buf_][ilA * 9 + cgA];                               \
            float4 vr = Stg4[buf_][(6 + jA) * 9 + cgA];                          \
            ushort4 o;                                                           \
            o.x = f2bf(va.x * vr.x);                                             \
            o.y = f2bf(va.y * vr.y);                                             \
            o.z = f2bf(va.z * vr.z);                                             \
            o.w = f2bf(va.w * vr.w);                                             \
            *(ushort4*)&RelS[buf_][rowA][cgA * 4] = o;                           \
        }

    // box K-step rel columns: k_local = cgA*4 + t = uv = u*4+v, u=cgA, v=t
    #define REL_GEN_BOX(buf_) {                                                  \
            ushort4 o = {0, 0, 0, 0};                                            \
            if (cgA < 4) {                                                       \
                float4 bi = *(const float4*)(boxB + iA * 4);                     \
                float4 bj = *(const float4*)(boxB + jA * 4);                     \
                float biu = (cgA == 0) ? bi.x : (cgA == 1) ? bi.y                \
                          : (cgA == 2) ? bi.z : bi.w;                            \
                o.x = f2bf(biu * bj.x);                                          \
                o.y = f2bf(biu * bj.y);                                          \
                o.z = f2bf(biu * bj.z);                                          \
                o.w = f2bf(biu * bj.w);                                          \
            }                                                                    \
            *(ushort4*)&RelS[buf_][rowA][cgA * 4] = o;                           \
        }

    // ---- prologue: RelS[0], Stg[1], Bs[0]
    STAGE_LOAD(0)
    STAGE_WRITE(0)
    STAGE_LOAD(32)
    __syncthreads();          // Stg[0] visible
    REL_GEN(0)
    STAGE_WRITE(1)
    ISSUE_B(0, 0)

    for (int k = 0; k <= 64; ++k) {
        const int cur = k & 1, nxt = cur ^ 1;
        __syncthreads();      // Bs[cur] drained; RelS[cur], Stg[nxt] visible
        if (k < 62) STAGE_LOAD((k + 2) * 32)    // issue global loads (sreg0)
        if (k < 64) ISSUE_B((k + 1) * 32, nxt)  // DMA for next step
        // af reads issued early: consumed by MFMA ~10 LDS-ops later
        bf16x8 af[4];
        #pragma unroll
        for (int mt = 0; mt < 4; ++mt)
            af[mt] = *(bf16x8*)&RelS[cur][wm * 64 + mt * 16 + fr][fq * 8];
        // REL_GEN fills the af-read latency window (independent buffers)
        if (k < 63) REL_GEN(nxt)
        else if (k == 63) REL_GEN_BOX(nxt)
        __builtin_amdgcn_s_setprio(1);
        #pragma unroll
        for (int nt = 0; nt < 4; ++nt) {
            bf16x8 bfv = *(bf16x8*)&Bs[cur][wn * 2048 + nt * 512 + bco];
            #pragma unroll
            for (int mt = 0; mt < 4; ++mt)
                acc[mt][nt] = __builtin_amdgcn_mfma_f32_16x16x32_bf16(af[mt], bfv, acc[mt][nt], 0, 0, 0);
        }
        __builtin_amdgcn_s_setprio(0);
        if (k < 62) STAGE_WRITE(cur)   // vmcnt wait + write, after MFMA (T14)
    }

    // epilogue: score_row = sum_cols W1*tanh(H + b0); b1 softmax-invariant
    float b0v[4], w1v[4];
    #pragma unroll
    for (int nt = 0; nt < 4; ++nt) {
        int col = wn * 64 + nt * 16 + fr;
        b0v[nt] = b0[col];
        w1v[nt] = W1[col];
    }
    #pragma unroll
    for (int mt = 0; mt < 4; ++mt) {
        #pragma unroll
        for (int reg = 0; reg < 4; ++reg) {
            float p = 0.f;
            #pragma unroll
            for (int nt = 0; nt < 4; ++nt)
                p += w1v[nt] * tanhf(acc[mt][nt][reg] + b0v[nt]);
            p += __shfl_xor(p, 1, 64);
            p += __shfl_xor(p, 2, 64);
            p += __shfl_xor(p, 4, 64);
            p += __shfl_xor(p, 8, 64);
            if (fr == 0)
                atomicAdd(&scoreS[wm * 64 + mt * 16 + fq * 4 + reg], p);
        }
    }
    __syncthreads();
    if (tid < 128 && p0 + tid < kPairs)
        scores[(size_t)b * kPairs + p0 + tid] = scoreS[tid];
}

// ---------------------------------------------------------------------------
// K5: softmax over j + abox[bi,:] = sum_j att[bi,j] * box[b,j,:]
// ---------------------------------------------------------------------------
__global__ __launch_bounds__(64)
void k5_softmax(const float* __restrict__ scores, const float* __restrict__ box,
                float* __restrict__ att, float* __restrict__ abox)
{
    const int bi = blockIdx.x;
    const int b  = bi / kN;
    const int tid = threadIdx.x;
    float s = (tid < kN) ? scores[(size_t)bi * kN + tid] : -1e30f;
    float m = s;
    #pragma unroll
    for (int off = 32; off >= 1; off >>= 1)
        m = fmaxf(m, __shfl_xor(m, off, 64));
    float e = (tid < kN) ? expf(s - m) : 0.f;
    float sum = e;
    #pragma unroll
    for (int off = 32; off >= 1; off >>= 1)
        sum += __shfl_xor(sum, off, 64);
    float a = e / sum;
    if (tid < kN) att[(size_t)bi * kN + tid] = a;

    float4 bx = {0.f, 0.f, 0.f, 0.f};
    if (tid < kN) bx = *(const float4*)(box + (size_t)(b * kN + tid) * 4);
    bx.x *= a; bx.y *= a; bx.z *= a; bx.w *= a;
    #pragma unroll
    for (int off = 32; off >= 1; off >>= 1) {
        bx.x += __shfl_xor(bx.x, off, 64);
        bx.y += __shfl_xor(bx.y, off, 64);
        bx.z += __shfl_xor(bx.z, off, 64);
        bx.w += __shfl_xor(bx.w, off, 64);
    }
    if (tid == 0) *(float4*)(abox + (size_t)bi * 4) = bx;
}

// ---------------------------------------------------------------------------
// K6: rank-4 box term.  out[b,i,d] = obj + fused + ra_i[d]*(att_i @ RB)[d]
//   + (box_i @ Wba)[d] * (abox_i @ Wbb)[d]       (abox_i = att_i @ box)
// ---------------------------------------------------------------------------
__global__ __launch_bounds__(256)
void k6_output(const float* __restrict__ obj, const unsigned short* __restrict__ fusedb,
               const float* __restrict__ ra, const float* __restrict__ rb,
               const float* __restrict__ att, const float* __restrict__ box,
               const float* __restrict__ abox,
               const float* __restrict__ Wba, const float* __restrict__ Wbb,
               float* __restrict__ out)
{
    __shared__ float attS[kN];
    const int bi = blockIdx.x;
    const int b = bi / kN;
    const int tid = threadIdx.x;
    if (tid < kN) attS[tid] = att[(size_t)bi * kN + tid];
    __syncthreads();
    const float4 bxi = *(const float4*)(box  + (size_t)bi * 4);
    const float4 axi = *(const float4*)(abox + (size_t)bi * 4);
    for (int d = tid; d < kD; d += 256) {
        float s1 = 0.f;
        #pragma unroll 4
        for (int j = 0; j < kN; ++j)
            s1 = fmaf(attS[j], rb[(size_t)(b * kN + j) * kD + d], s1);
        float bav = bxi.x * Wba[d] + bxi.y * Wba[kD + d]
                  + bxi.z * Wba[2 * kD + d] + bxi.w * Wba[3 * kD + d];
        float s2  = axi.x * Wbb[d] + axi.y * Wbb[kD + d]
                  + axi.z * Wbb[2 * kD + d] + axi.w * Wbb[3 * kD + d];
        size_t o = (size_t)bi * kD + d;
        float fv = __uint_as_float((u32)fusedb[o] << 16);
        out[o] = obj[o] + fv + ra[o] * s1 + bav * s2;
    }
}

// ---------------------------------------------------------------------------
extern "C" void kernel_launch(void* const* d_in, const int* in_sizes, int n_in,
                              void* d_out, int out_size, void* d_ws, size_t ws_size,
                              hipStream_t stream)
{
    const float* q   = (const float*)d_in[0];
    const float* obj = (const float*)d_in[1];
    const float* box = (const float*)d_in[2];
    const float* Wq  = (const float*)d_in[3];
    const float* Wo  = (const float*)d_in[4];
    const float* Wfa = (const float*)d_in[5];
    const float* Wfb = (const float*)d_in[6];
    const float* Wba = (const float*)d_in[7];
    const float* Wbb = (const float*)d_in[8];
    const float* W0  = (const float*)d_in[9];
    const float* b0v = (const float*)d_in[10];
    const float* W1  = (const float*)d_in[11];
    // d_in[12] = b1 (softmax-invariant), d_in[13..14] scalars: unused
    float* out = (float*)d_out;

    const size_t nBD = (size_t)kBN * kD;
    float* ws = (float*)d_ws;
    size_t off = 0;
    float* ra     = ws + off; off += nBD;
    float* rb     = ws + off; off += nBD;
    float* scores = ws + off; off += (size_t)kBN * kN;
    float* att    = ws + off; off += (size_t)kBN * kN;
    float* abox   = ws + off; off += (size_t)kBN * 4;
    float* Gpart  = ws + off; off += (size_t)16 * 16 * kDatt;

    unsigned short* us = (unsigned short*)(ws + off);
    size_t uoff = 0;
    unsigned short* W0T     = us + uoff; uoff += (size_t)kDatt * kD;
    unsigned short* W0s     = us + uoff; uoff += (size_t)65 * 16384;  // 64 K-blocks + G-block
    unsigned short* q_bf    = us + uoff; uoff += nBD;
    unsigned short* obj_bf  = us + uoff; uoff += nBD;
    unsigned short* fusedbf = us + uoff; uoff += nBD;
    unsigned short* WqT     = us + uoff; uoff += (size_t)kD * kD;
    unsigned short* WoT     = us + uoff; uoff += (size_t)kD * kD;
    // WfaT/WfbT alias q_bf/obj_bf (dead after k1; stream order guarantees safety)
    unsigned short* WfaT = q_bf;
    unsigned short* WfbT = obj_bf;

    const int n4 = (int)(nBD / 4);
    kcvt<<<dim3((n4 + 255) / 256), 256, 0, stream>>>(q,   q_bf,   n4);
    kcvt<<<dim3((n4 + 255) / 256), 256, 0, stream>>>(obj, obj_bf, n4);
    ktrp<<<dim3(32, 32), 256, 0, stream>>>(Wq, WqT, kD);
    ktrp<<<dim3(32, 32), 256, 0, stream>>>(Wo, WoT, kD);
    ktrp<<<dim3(32, 8),  256, 0, stream>>>(W0, W0T, kDatt);
    krepack_w0<<<dim3(kD / 32, kDatt / 16), 64, 0, stream>>>(W0T, W0s);
    kgbox<<<dim3(8, 16), 256, 0, stream>>>(Wba, Wbb, W0, Gpart);
    krepack_g<<<dim3(32), 64, 0, stream>>>(Gpart, W0s);

    k1_dual_mfma<<<dim3(kD / 64, kBN / 128), 256, 0, stream>>>(q_bf, WqT, obj_bf, WoT, fusedbf);

    ktrp<<<dim3(32, 32), 256, 0, stream>>>(Wfa, WfaT, kD);
    ktrp<<<dim3(32, 32), 256, 0, stream>>>(Wfb, WfbT, kD);

    k2_dual_mfma<<<dim3(kD / 64, kBN / 128), 256, 0, stream>>>(fusedbf, WfaT, WfbT, ra, rb);

    k4_scores_mfma<<<dim3(kB * 11), 1024, 0, stream>>>(ra, rb, box, W0s, b0v, W1, scores);
    k5_softmax<<<kBN, 64, 0, stream>>>(scores, box, att, abox);
    k6_output<<<kBN, 256, 0, stream>>>(obj, fusedbf, ra, rb, att, box, abox, Wba, Wbb, out);
}

// Round 8
// 645.744 us; speedup vs baseline: 1.0195x; 1.0195x over previous
//
#include <hip/hip_runtime.h>
#include <hip/hip_bf16.h>
#include <math.h>

constexpr int kB    = 64;
constexpr int kN    = 36;
constexpr int kBN   = kB * kN;   // 2304
constexpr int kD    = 2048;
constexpr int kDatt = 512;
constexpr int kPairs = kN * kN;  // 1296

using bf16x8 = __attribute__((ext_vector_type(8))) short;
using f32x4  = __attribute__((ext_vector_type(4))) float;

typedef unsigned int u32;
typedef __attribute__((address_space(3))) u32 lds_u32;
typedef const __attribute__((address_space(1))) u32 glb_u32;

__device__ inline unsigned short f2bf(float f) {
    union { float f; unsigned u; } v; v.f = f;
    unsigned r = v.u + 0x7FFFu + ((v.u >> 16) & 1u);   // RNE
    return (unsigned short)(r >> 16);
}

// ---------------------------------------------------------------------------
// kcvt: f32 -> bf16 elementwise
// ---------------------------------------------------------------------------
__global__ __launch_bounds__(256)
void kcvt(const float* __restrict__ x, unsigned short* __restrict__ y, int n4)
{
    int i = blockIdx.x * 256 + threadIdx.x;
    if (i < n4) {
        float4 v = ((const float4*)x)[i];
        ushort4 o = {f2bf(v.x), f2bf(v.y), f2bf(v.z), f2bf(v.w)};
        ((ushort4*)y)[i] = o;
    }
}

// ---------------------------------------------------------------------------
// kzero: zero an f32 buffer (scores is accumulated via atomics by k4)
// ---------------------------------------------------------------------------
__global__ __launch_bounds__(256)
void kzero(float* __restrict__ p, int n)
{
    int i = blockIdx.x * 256 + threadIdx.x;
    if (i < n) p[i] = 0.f;
}

// ---------------------------------------------------------------------------
// ktrp: W[kD][nt] f32 -> WT[nt][kD] bf16 (transpose + convert)
// ---------------------------------------------------------------------------
__global__ __launch_bounds__(256)
void ktrp(const float* __restrict__ W, unsigned short* __restrict__ WT, int nt)
{
    __shared__ float T[64][65];
    const int k0 = blockIdx.x * 64;
    const int n0 = blockIdx.y * 64;
    const int c = threadIdx.x & 63, r0 = threadIdx.x >> 6;
    #pragma unroll
    for (int rr = 0; rr < 64; rr += 4)
        T[r0 + rr][c] = W[(size_t)(k0 + r0 + rr) * nt + n0 + c];
    __syncthreads();
    #pragma unroll
    for (int rr = 0; rr < 64; rr += 4)
        WT[(size_t)(n0 + r0 + rr) * kD + k0 + c] = f2bf(T[c][r0 + rr]);
}

// ---------------------------------------------------------------------------
// krepack_w0: W0T[col][k] bf16 -> W0s, k4-tile-major with the conflict-free
// granule permutation baked in (see k4 header).
// ---------------------------------------------------------------------------
__global__ __launch_bounds__(64)
void krepack_w0(const unsigned short* __restrict__ W0T, unsigned short* __restrict__ W0s)
{
    const int kb    = blockIdx.x;   // 0..63  : K-block (32 k's)
    const int chunk = blockIdx.y;   // 0..31  : 16-row chunk
    const int g     = threadIdx.x;  // 0..63  : granule
    const int row = chunk * 16 + (g & 7) + ((g >> 5) << 3);
    const int cg8 = ((g >> 3) & 3) * 8;
    const uint4 v = *(const uint4*)&W0T[(size_t)row * kD + kb * 32 + cg8];
    *(uint4*)&W0s[(size_t)kb * 16384 + chunk * 512 + g * 8] = v;
}

// ---------------------------------------------------------------------------
// kgbox (parallel): Gpart[kc][uv][c] = sum_{k in chunk kc}
//   Wba[u,k]*Wbb[v,k]*W0[k,c].  Grid (8 c-tiles, 16 k-chunks) x 256 thr.
// ---------------------------------------------------------------------------
__global__ __launch_bounds__(256)
void kgbox(const float* __restrict__ Wba, const float* __restrict__ Wbb,
           const float* __restrict__ W0, float* __restrict__ Gpart)
{
    __shared__ float red[4][64][17];
    const int ct = blockIdx.x;            // 0..7  : 64-col tile
    const int kc = blockIdx.y;            // 0..15 : 128-k chunk
    const int cl = threadIdx.x & 63;
    const int kq = threadIdx.x >> 6;      // 0..3
    const int c  = ct * 64 + cl;

    float acc[16];
    #pragma unroll
    for (int t = 0; t < 16; ++t) acc[t] = 0.f;

    const int kbase = kc * 128 + kq * 32;
    for (int kk = 0; kk < 32; ++kk) {
        int k = kbase + kk;
        float w0 = W0[(size_t)k * kDatt + c];
        float a0 = Wba[k], a1 = Wba[kD + k], a2 = Wba[2 * kD + k], a3 = Wba[3 * kD + k];
        float b0 = Wbb[k] * w0, b1 = Wbb[kD + k] * w0,
              b2 = Wbb[2 * kD + k] * w0, b3 = Wbb[3 * kD + k] * w0;
        acc[0]  = fmaf(a0, b0, acc[0]);  acc[1]  = fmaf(a0, b1, acc[1]);
        acc[2]  = fmaf(a0, b2, acc[2]);  acc[3]  = fmaf(a0, b3, acc[3]);
        acc[4]  = fmaf(a1, b0, acc[4]);  acc[5]  = fmaf(a1, b1, acc[5]);
        acc[6]  = fmaf(a1, b2, acc[6]);  acc[7]  = fmaf(a1, b3, acc[7]);
        acc[8]  = fmaf(a2, b0, acc[8]);  acc[9]  = fmaf(a2, b1, acc[9]);
        acc[10] = fmaf(a2, b2, acc[10]); acc[11] = fmaf(a2, b3, acc[11]);
        acc[12] = fmaf(a3, b0, acc[12]); acc[13] = fmaf(a3, b1, acc[13]);
        acc[14] = fmaf(a3, b2, acc[14]); acc[15] = fmaf(a3, b3, acc[15]);
    }
    #pragma unroll
    for (int t = 0; t < 16; ++t) red[kq][cl][t] = acc[t];
    __syncthreads();
    #pragma unroll
    for (int t = 0; t < 4; ++t) {
        int s = threadIdx.x + t * 256;    // 0..1023 : cc*16 + uv
        int cc = s >> 4, uv = s & 15;
        float v = red[0][cc][uv] + red[1][cc][uv] + red[2][cc][uv] + red[3][cc][uv];
        Gpart[((size_t)kc * 16 + uv) * kDatt + ct * 64 + cc] = v;
    }
}

// ---------------------------------------------------------------------------
// krepack_g: sum the 16 k-chunk partials (f32) -> W0s K-block 64 (bf16,
// permuted layout, k_local = uv for uv<16, zero for 16..31).
// ---------------------------------------------------------------------------
__global__ __launch_bounds__(64)
void krepack_g(const float* __restrict__ Gpart, unsigned short* __restrict__ W0s)
{
    const int chunk = blockIdx.x;   // 0..31 : 16-col chunk
    const int g     = threadIdx.x;  // 0..63 : granule
    const int col = chunk * 16 + (g & 7) + ((g >> 5) << 3);
    const int kg  = (g >> 3) & 3;
    unsigned short o[8];
    #pragma unroll
    for (int e = 0; e < 8; ++e) {
        int kl = kg * 8 + e;
        if (kl < 16) {
            float s = 0.f;
            #pragma unroll
            for (int kc = 0; kc < 16; ++kc)
                s += Gpart[((size_t)kc * 16 + kl) * kDatt + col];
            o[e] = f2bf(s);
        } else o[e] = 0;
    }
    *(uint4*)&W0s[(size_t)64 * 16384 + chunk * 512 + g * 8] = *(uint4*)o;
}

// ---------------------------------------------------------------------------
// Staging helpers for k1/k2: Rx32 bf16 tiles via global_load_lds width=16.
// ---------------------------------------------------------------------------
__device__ inline void stage128(const unsigned short* __restrict__ g,
                                int grow0, int k0,
                                unsigned short* lds, int w, int lane)
{
    const int sr = lane >> 2, sc = (lane & 3) * 8;
    #pragma unroll
    for (int t = 0; t < 2; ++t) {
        int r = w * 32 + t * 16;
        const unsigned short* gp = g + (size_t)(grow0 + r + sr) * kD + k0 + sc;
        __builtin_amdgcn_global_load_lds((glb_u32*)gp, (lds_u32*)(lds + r * 32), 16, 0, 0);
    }
}
__device__ inline void stage64(const unsigned short* __restrict__ g,
                               int grow0, int k0,
                               unsigned short* lds, int w, int lane)
{
    const int sr = lane >> 2, sc = (lane & 3) * 8;
    int r = w * 16;
    const unsigned short* gp = g + (size_t)(grow0 + r + sr) * kD + k0 + sc;
    __builtin_amdgcn_global_load_lds((glb_u32*)gp, (lds_u32*)(lds + r * 32), 16, 0, 0);
}

// ---------------------------------------------------------------------------
// K1 (MFMA dual): fused_bf16 = bf16((Qb @ WqT') .* (Ob @ WoT')), 128x64 tile
// ---------------------------------------------------------------------------
__global__ __launch_bounds__(256, 2)
void k1_dual_mfma(const unsigned short* __restrict__ Qb,
                  const unsigned short* __restrict__ WqT,
                  const unsigned short* __restrict__ Ob,
                  const unsigned short* __restrict__ WoT,
                  unsigned short* __restrict__ fusedb)
{
    __shared__ __align__(16) unsigned short As1[128][32];
    __shared__ __align__(16) unsigned short As2[128][32];
    __shared__ __align__(16) unsigned short Bs1[64][32];
    __shared__ __align__(16) unsigned short Bs2[64][32];

    const int tid = threadIdx.x;
    const int lane = tid & 63;
    const int w = tid >> 6;
    const int wm = w >> 1, wn = w & 1;
    const int row0 = blockIdx.y * 128;
    const int col0 = blockIdx.x * 64;

    f32x4 acc1[4][2], acc2[4][2];
    #pragma unroll
    for (int mt = 0; mt < 4; ++mt)
        #pragma unroll
        for (int nt = 0; nt < 2; ++nt) { acc1[mt][nt] = (f32x4)(0.f); acc2[mt][nt] = (f32x4)(0.f); }

    const int fr = lane & 15, ko = (lane >> 4) * 8;

    for (int k0 = 0; k0 < kD; k0 += 32) {
        stage128(Qb,  row0, k0, &As1[0][0], w, lane);
        stage128(Ob,  row0, k0, &As2[0][0], w, lane);
        stage64 (WqT, col0, k0, &Bs1[0][0], w, lane);
        stage64 (WoT, col0, k0, &Bs2[0][0], w, lane);
        __syncthreads();

        bf16x8 a1[4], a2[4];
        #pragma unroll
        for (int mt = 0; mt < 4; ++mt) {
            a1[mt] = *(bf16x8*)&As1[wm * 64 + mt * 16 + fr][ko];
            a2[mt] = *(bf16x8*)&As2[wm * 64 + mt * 16 + fr][ko];
        }
        #pragma unroll
        for (int nt = 0; nt < 2; ++nt) {
            bf16x8 b1 = *(bf16x8*)&Bs1[wn * 32 + nt * 16 + fr][ko];
            bf16x8 b2 = *(bf16x8*)&Bs2[wn * 32 + nt * 16 + fr][ko];
            #pragma unroll
            for (int mt = 0; mt < 4; ++mt) {
                acc1[mt][nt] = __builtin_amdgcn_mfma_f32_16x16x32_bf16(a1[mt], b1, acc1[mt][nt], 0, 0, 0);
                acc2[mt][nt] = __builtin_amdgcn_mfma_f32_16x16x32_bf16(a2[mt], b2, acc2[mt][nt], 0, 0, 0);
            }
        }
        __syncthreads();
    }

    const int fq = lane >> 4;
    #pragma unroll
    for (int mt = 0; mt < 4; ++mt)
        #pragma unroll
        for (int nt = 0; nt < 2; ++nt) {
            int row = row0 + wm * 64 + mt * 16 + fq * 4;
            int col = col0 + wn * 32 + nt * 16 + fr;
            #pragma unroll
            for (int reg = 0; reg < 4; ++reg) {
                float v = acc1[mt][nt][reg] * acc2[mt][nt][reg];
                fusedb[(size_t)(row + reg) * kD + col] = f2bf(v);
            }
        }
}

// ---------------------------------------------------------------------------
// K2 (MFMA dual-B): ra = Fb @ WfaT', rb = Fb @ WfbT', 128x64 tile
// ---------------------------------------------------------------------------
__global__ __launch_bounds__(256, 2)
void k2_dual_mfma(const unsigned short* __restrict__ Fb,
                  const unsigned short* __restrict__ WfaT,
                  const unsigned short* __restrict__ WfbT,
                  float* __restrict__ ra, float* __restrict__ rb)
{
    __shared__ __align__(16) unsigned short As [128][32];
    __shared__ __align__(16) unsigned short Bs1[64][32];
    __shared__ __align__(16) unsigned short Bs2[64][32];

    const int tid = threadIdx.x;
    const int lane = tid & 63;
    const int w = tid >> 6;
    const int wm = w >> 1, wn = w & 1;
    const int row0 = blockIdx.y * 128;
    const int col0 = blockIdx.x * 64;

    f32x4 acc1[4][2], acc2[4][2];
    #pragma unroll
    for (int mt = 0; mt < 4; ++mt)
        #pragma unroll
        for (int nt = 0; nt < 2; ++nt) { acc1[mt][nt] = (f32x4)(0.f); acc2[mt][nt] = (f32x4)(0.f); }

    const int fr = lane & 15, ko = (lane >> 4) * 8;

    for (int k0 = 0; k0 < kD; k0 += 32) {
        stage128(Fb,   row0, k0, &As [0][0], w, lane);
        stage64 (WfaT, col0, k0, &Bs1[0][0], w, lane);
        stage64 (WfbT, col0, k0, &Bs2[0][0], w, lane);
        __syncthreads();

        bf16x8 a[4];
        #pragma unroll
        for (int mt = 0; mt < 4; ++mt)
            a[mt] = *(bf16x8*)&As[wm * 64 + mt * 16 + fr][ko];
        #pragma unroll
        for (int nt = 0; nt < 2; ++nt) {
            bf16x8 b1 = *(bf16x8*)&Bs1[wn * 32 + nt * 16 + fr][ko];
            bf16x8 b2 = *(bf16x8*)&Bs2[wn * 32 + nt * 16 + fr][ko];
            #pragma unroll
            for (int mt = 0; mt < 4; ++mt) {
                acc1[mt][nt] = __builtin_amdgcn_mfma_f32_16x16x32_bf16(a[mt], b1, acc1[mt][nt], 0, 0, 0);
                acc2[mt][nt] = __builtin_amdgcn_mfma_f32_16x16x32_bf16(a[mt], b2, acc2[mt][nt], 0, 0, 0);
            }
        }
        __syncthreads();
    }

    const int fq = lane >> 4;
    #pragma unroll
    for (int mt = 0; mt < 4; ++mt)
        #pragma unroll
        for (int nt = 0; nt < 2; ++nt) {
            int row = row0 + wm * 64 + mt * 16 + fq * 4;
            int col = col0 + wn * 32 + nt * 16 + fr;
            #pragma unroll
            for (int reg = 0; reg < 4; ++reg) {
                size_t o = (size_t)(row + reg) * kD + col;
                ra[o] = acc1[mt][nt][reg];
                rb[o] = acc2[mt][nt][reg];
            }
        }
}

// ---------------------------------------------------------------------------
// K4 v11: N-split -> 2 independent blocks per CU so barriers decouple.
//
// v10 showed intra-block scheduling is null: all waves meet the same
// __syncthreads, so each step's DMA-drain + LDS latency tail serializes the
// whole CU. v11 splits the 512 cols into 2 col-blocks of 256: 512-thread
// blocks (8 waves, wave tile 64x64, acc 4x4), LDS 64.4 KB -> 2 blocks/CU
// (16 waves = 4/SIMD, same occupancy). Co-resident waves now belong to
// DIFFERENT barriers -> block B runs while block A drains.
//
// Cost: REL_GEN + Stg staging duplicated per CU (identical pair-rows in
// both col-blocks) -- +~20% LDS volume at ~55% port util. To hold the
// arch+acc <= 128 VGPR cliff (4 waves/SIMD), rel-gen is ONE ushort8 slot
// per thread (128 rows x 4 col-pairs = 512 slots; b128 RelS writes).
// Scores accumulate across the 2 col-blocks via global atomicAdd (kzero
// pre-zeroes). Grid 1408 = 8 XCD x 176; col-block pairs stay same-XCD.
// ---------------------------------------------------------------------------
__global__ __launch_bounds__(512, 4)
void k4_scores_mfma(const float* __restrict__ ra, const float* __restrict__ rb,
                    const float* __restrict__ box,
                    const unsigned short* __restrict__ W0s,
                    const float* __restrict__ b0, const float* __restrict__ W1,
                    float* __restrict__ scores)
{
    __shared__ __align__(16) unsigned short Bs[2][256 * 32];  // 32 KB
    __shared__ __align__(16) unsigned short RelS[2][128][40]; // 20 KB
    __shared__ __align__(16) float4 Stg4[2][378];             // 12 KB : 42 rows x (8+1) f4
    __shared__ float scoreS[128];

    const int tid  = threadIdx.x;
    const int lane = tid & 63;
    const int w    = tid >> 6;        // 0..7
    const int wm   = w >> 2;          // 0..1 : M-half (64 rows)
    const int wn   = w & 3;           // 0..3 : 64-col quarter of this col-block

    // XCD-chunked swizzle: 1408 = 8 XCDs x 176; col-block pairs adjacent
    const int work = (blockIdx.x & 7) * 176 + (blockIdx.x >> 3);
    const int colb = work & 1;        // 0/1 : which 256-col half
    const int wt   = work >> 1;
    const int b    = wt / 11;
    const int tile = wt - b * 11;     // 0..10 (tile 10: 16 valid rows)
    const int p0   = tile * 128;
    const int i0   = p0 / kN;

    const float* raB  = ra  + (size_t)b * kN * kD;
    const float* rbB  = rb  + (size_t)b * kN * kD;
    const float* boxB = box + (size_t)b * kN * 4;

    // ---- stage slots: 336 = 42 rows x 8 f4 (rows 0..5 = i-rows of ra,
    //      rows 6..41 = j-rows of rb); Stg row stride 9 f4 (pad)
    const bool hasStage = (tid < 336);
    const float* sptr;
    int sdst;
    {
        int s = hasStage ? tid : 335;
        int row = s >> 3, q = s & 7;
        int grow; const float* base;
        if (row < 6) {
            int il = (row < 5) ? row : 4;
            grow = i0 + il; if (grow > kN - 1) grow = kN - 1;
            base = raB;
        } else {
            grow = row - 6;
            base = rbB;
        }
        sptr = base + (size_t)grow * kD + q * 4;
        sdst = row * 9 + q;
    }

    // ---- Rel-gen slot: 512 = 128 rows x 4 col-pairs (8 k's each); 1/thread
    int rowA, cg2, iA, jA, sA, sR;
    {
        rowA = tid >> 2; cg2 = tid & 3;
        int p = p0 + rowA; if (p >= kPairs) p = kPairs - 1;
        iA = p / kN;
        jA = p - iA * kN;
        int ilA = iA - i0;
        sA = ilA * 9 + cg2 * 2;
        sR = (6 + jA) * 9 + cg2 * 2;
    }

    const int fr = lane & 15, fq = lane >> 4;
    const int bco = ((fr & 7) << 3) + ((fr >> 3) << 8) + (fq << 6);

    f32x4 acc[4][4];
    #pragma unroll
    for (int mt = 0; mt < 4; ++mt)
        #pragma unroll
        for (int nt = 0; nt < 4; ++nt)
            acc[mt][nt] = (f32x4)(0.f);

    if (tid < 128) scoreS[tid] = 0.f;

    float4 sreg0;

    #define ISSUE_B(k0_, buf_)                                                   \
        _Pragma("unroll")                                                        \
        for (int t = 0; t < 2; ++t) {                                            \
            int ch = w * 2 + t;                                                  \
            const unsigned short* gp = W0s + (size_t)((k0_) >> 5) * 16384        \
                                       + (colb * 16 + ch) * 512 + lane * 8;      \
            __builtin_amdgcn_global_load_lds((glb_u32*)gp,                       \
                (lds_u32*)&Bs[buf_][ch * 512], 16, 0, 0);                        \
        }

    #define STAGE_LOAD(k0_) {                                                    \
            if (hasStage) sreg0 = *(const float4*)(sptr + (k0_));                \
        }

    #define STAGE_WRITE(buf_) {                                                  \
            if (hasStage) Stg4[buf_][sdst] = sreg0;                              \
        }

    #define REL_GEN(buf_) {                                                      \
            float4 va0 = Stg4[buf_][sA],     va1 = Stg4[buf_][sA + 1];           \
            float4 vr0 = Stg4[buf_][sR],     vr1 = Stg4[buf_][sR + 1];           \
            unsigned short o[8];                                                 \
            o[0] = f2bf(va0.x * vr0.x); o[1] = f2bf(va0.y * vr0.y);              \
            o[2] = f2bf(va0.z * vr0.z); o[3] = f2bf(va0.w * vr0.w);              \
            o[4] = f2bf(va1.x * vr1.x); o[5] = f2bf(va1.y * vr1.y);              \
            o[6] = f2bf(va1.z * vr1.z); o[7] = f2bf(va1.w * vr1.w);              \
            *(bf16x8*)&RelS[buf_][rowA][cg2 * 8] = *(bf16x8*)o;                  \
        }

    // box K-step: k_local c = cg2*8+e -> uv = c (u=c>>2, v=c&3) for c<16
    #define REL_GEN_BOX(buf_) {                                                  \
            unsigned short o[8] = {0, 0, 0, 0, 0, 0, 0, 0};                      \
            if (cg2 < 2) {                                                       \
                float4 bj = *(const float4*)(boxB + jA * 4);                     \
                float biu0 = boxB[iA * 4 + cg2 * 2];                             \
                float biu1 = boxB[iA * 4 + cg2 * 2 + 1];                         \
                o[0] = f2bf(biu0 * bj.x); o[1] = f2bf(biu0 * bj.y);              \
                o[2] = f2bf(biu0 * bj.z); o[3] = f2bf(biu0 * bj.w);              \
                o[4] = f2bf(biu1 * bj.x); o[5] = f2bf(biu1 * bj.y);              \
                o[6] = f2bf(biu1 * bj.z); o[7] = f2bf(biu1 * bj.w);              \
            }                                                                    \
            *(bf16x8*)&RelS[buf_][rowA][cg2 * 8] = *(bf16x8*)o;                  \
        }

    // ---- prologue: RelS[0], Stg[1], Bs[0]
    STAGE_LOAD(0)
    STAGE_WRITE(0)
    STAGE_LOAD(32)
    __syncthreads();          // Stg[0] visible
    REL_GEN(0)
    STAGE_WRITE(1)
    ISSUE_B(0, 0)

    for (int k = 0; k <= 64; ++k) {
        const int cur = k & 1, nxt = cur ^ 1;
        __syncthreads();      // Bs[cur] drained; RelS[cur], Stg[nxt] visible
        if (k < 62) STAGE_LOAD((k + 2) * 32)
        if (k < 64) ISSUE_B((k + 1) * 32, nxt)
        bf16x8 af[4];
        #pragma unroll
        for (int mt = 0; mt < 4; ++mt)
            af[mt] = *(bf16x8*)&RelS[cur][wm * 64 + mt * 16 + fr][fq * 8];
        if (k < 63) REL_GEN(nxt)
        else if (k == 63) REL_GEN_BOX(nxt)
        __builtin_amdgcn_s_setprio(1);
        #pragma unroll
        for (int nt = 0; nt < 4; ++nt) {
            bf16x8 bfv = *(bf16x8*)&Bs[cur][wn * 2048 + nt * 512 + bco];
            #pragma unroll
            for (int mt = 0; mt < 4; ++mt)
                acc[mt][nt] = __builtin_amdgcn_mfma_f32_16x16x32_bf16(af[mt], bfv, acc[mt][nt], 0, 0, 0);
        }
        __builtin_amdgcn_s_setprio(0);
        if (k < 62) STAGE_WRITE(cur)
    }

    // epilogue: partial score over this col-block's 256 cols
    float b0v[4], w1v[4];
    #pragma unroll
    for (int nt = 0; nt < 4; ++nt) {
        int col = colb * 256 + wn * 64 + nt * 16 + fr;
        b0v[nt] = b0[col];
        w1v[nt] = W1[col];
    }
    #pragma unroll
    for (int mt = 0; mt < 4; ++mt) {
        #pragma unroll
        for (int reg = 0; reg < 4; ++reg) {
            float p = 0.f;
            #pragma unroll
            for (int nt = 0; nt < 4; ++nt)
                p += w1v[nt] * tanhf(acc[mt][nt][reg] + b0v[nt]);
            p += __shfl_xor(p, 1, 64);
            p += __shfl_xor(p, 2, 64);
            p += __shfl_xor(p, 4, 64);
            p += __shfl_xor(p, 8, 64);
            if (fr == 0)
                atomicAdd(&scoreS[wm * 64 + mt * 16 + fq * 4 + reg], p);
        }
    }
    __syncthreads();
    if (tid < 128 && p0 + tid < kPairs)
        atomicAdd(&scores[(size_t)b * kPairs + p0 + tid], scoreS[tid]);
}

// ---------------------------------------------------------------------------
// K5: softmax over j + abox[bi,:] = sum_j att[bi,j] * box[b,j,:]
// ---------------------------------------------------------------------------
__global__ __launch_bounds__(64)
void k5_softmax(const float* __restrict__ scores, const float* __restrict__ box,
                float* __restrict__ att, float* __restrict__ abox)
{
    const int bi = blockIdx.x;
    const int b  = bi / kN;
    const int tid = threadIdx.x;
    float s = (tid < kN) ? scores[(size_t)bi * kN + tid] : -1e30f;
    float m = s;
    #pragma unroll
    for (int off = 32; off >= 1; off >>= 1)
        m = fmaxf(m, __shfl_xor(m, off, 64));
    float e = (tid < kN) ? expf(s - m) : 0.f;
    float sum = e;
    #pragma unroll
    for (int off = 32; off >= 1; off >>= 1)
        sum += __shfl_xor(sum, off, 64);
    float a = e / sum;
    if (tid < kN) att[(size_t)bi * kN + tid] = a;

    float4 bx = {0.f, 0.f, 0.f, 0.f};
    if (tid < kN) bx = *(const float4*)(box + (size_t)(b * kN + tid) * 4);
    bx.x *= a; bx.y *= a; bx.z *= a; bx.w *= a;
    #pragma unroll
    for (int off = 32; off >= 1; off >>= 1) {
        bx.x += __shfl_xor(bx.x, off, 64);
        bx.y += __shfl_xor(bx.y, off, 64);
        bx.z += __shfl_xor(bx.z, off, 64);
        bx.w += __shfl_xor(bx.w, off, 64);
    }
    if (tid == 0) *(float4*)(abox + (size_t)bi * 4) = bx;
}

// ---------------------------------------------------------------------------
// K6: rank-4 box term.  out[b,i,d] = obj + fused + ra_i[d]*(att_i @ RB)[d]
//   + (box_i @ Wba)[d] * (abox_i @ Wbb)[d]       (abox_i = att_i @ box)
// ---------------------------------------------------------------------------
__global__ __launch_bounds__(256)
void k6_output(const float* __restrict__ obj, const unsigned short* __restrict__ fusedb,
               const float* __restrict__ ra, const float* __restrict__ rb,
               const float* __restrict__ att, const float* __restrict__ box,
               const float* __restrict__ abox,
               const float* __restrict__ Wba, const float* __restrict__ Wbb,
               float* __restrict__ out)
{
    __shared__ float attS[kN];
    const int bi = blockIdx.x;
    const int b = bi / kN;
    const int tid = threadIdx.x;
    if (tid < kN) attS[tid] = att[(size_t)bi * kN + tid];
    __syncthreads();
    const float4 bxi = *(const float4*)(box  + (size_t)bi * 4);
    const float4 axi = *(const float4*)(abox + (size_t)bi * 4);
    for (int d = tid; d < kD; d += 256) {
        float s1 = 0.f;
        #pragma unroll 4
        for (int j = 0; j < kN; ++j)
            s1 = fmaf(attS[j], rb[(size_t)(b * kN + j) * kD + d], s1);
        float bav = bxi.x * Wba[d] + bxi.y * Wba[kD + d]
                  + bxi.z * Wba[2 * kD + d] + bxi.w * Wba[3 * kD + d];
        float s2  = axi.x * Wbb[d] + axi.y * Wbb[kD + d]
                  + axi.z * Wbb[2 * kD + d] + axi.w * Wbb[3 * kD + d];
        size_t o = (size_t)bi * kD + d;
        float fv = __uint_as_float((u32)fusedb[o] << 16);
        out[o] = obj[o] + fv + ra[o] * s1 + bav * s2;
    }
}

// ---------------------------------------------------------------------------
extern "C" void kernel_launch(void* const* d_in, const int* in_sizes, int n_in,
                              void* d_out, int out_size, void* d_ws, size_t ws_size,
                              hipStream_t stream)
{
    const float* q   = (const float*)d_in[0];
    const float* obj = (const float*)d_in[1];
    const float* box = (const float*)d_in[2];
    const float* Wq  = (const float*)d_in[3];
    const float* Wo  = (const float*)d_in[4];
    const float* Wfa = (const float*)d_in[5];
    const float* Wfb = (const float*)d_in[6];
    const float* Wba = (const float*)d_in[7];
    const float* Wbb = (const float*)d_in[8];
    const float* W0  = (const float*)d_in[9];
    const float* b0v = (const float*)d_in[10];
    const float* W1  = (const float*)d_in[11];
    // d_in[12] = b1 (softmax-invariant), d_in[13..14] scalars: unused
    float* out = (float*)d_out;

    const size_t nBD = (size_t)kBN * kD;
    float* ws = (float*)d_ws;
    size_t off = 0;
    float* ra     = ws + off; off += nBD;
    float* rb     = ws + off; off += nBD;
    float* scores = ws + off; off += (size_t)kBN * kN;
    float* att    = ws + off; off += (size_t)kBN * kN;
    float* abox   = ws + off; off += (size_t)kBN * 4;
    float* Gpart  = ws + off; off += (size_t)16 * 16 * kDatt;

    unsigned short* us = (unsigned short*)(ws + off);
    size_t uoff = 0;
    unsigned short* W0T     = us + uoff; uoff += (size_t)kDatt * kD;
    unsigned short* W0s     = us + uoff; uoff += (size_t)65 * 16384;  // 64 K-blocks + G-block
    unsigned short* q_bf    = us + uoff; uoff += nBD;
    unsigned short* obj_bf  = us + uoff; uoff += nBD;
    unsigned short* fusedbf = us + uoff; uoff += nBD;
    unsigned short* WqT     = us + uoff; uoff += (size_t)kD * kD;
    unsigned short* WoT     = us + uoff; uoff += (size_t)kD * kD;
    // WfaT/WfbT alias q_bf/obj_bf (dead after k1; stream order guarantees safety)
    unsigned short* WfaT = q_bf;
    unsigned short* WfbT = obj_bf;

    const int n4 = (int)(nBD / 4);
    kcvt<<<dim3((n4 + 255) / 256), 256, 0, stream>>>(q,   q_bf,   n4);
    kcvt<<<dim3((n4 + 255) / 256), 256, 0, stream>>>(obj, obj_bf, n4);
    ktrp<<<dim3(32, 32), 256, 0, stream>>>(Wq, WqT, kD);
    ktrp<<<dim3(32, 32), 256, 0, stream>>>(Wo, WoT, kD);
    ktrp<<<dim3(32, 8),  256, 0, stream>>>(W0, W0T, kDatt);
    krepack_w0<<<dim3(kD / 32, kDatt / 16), 64, 0, stream>>>(W0T, W0s);
    kgbox<<<dim3(8, 16), 256, 0, stream>>>(Wba, Wbb, W0, Gpart);
    krepack_g<<<dim3(32), 64, 0, stream>>>(Gpart, W0s);
    kzero<<<dim3((kBN * kN + 255) / 256), 256, 0, stream>>>(scores, kBN * kN);

    k1_dual_mfma<<<dim3(kD / 64, kBN / 128), 256, 0, stream>>>(q_bf, WqT, obj_bf, WoT, fusedbf);

    ktrp<<<dim3(32, 32), 256, 0, stream>>>(Wfa, WfaT, kD);
    ktrp<<<dim3(32, 32), 256, 0, stream>>>(Wfb, WfbT, kD);

    k2_dual_mfma<<<dim3(kD / 64, kBN / 128), 256, 0, stream>>>(fusedbf, WfaT, WfbT, ra, rb);

    k4_scores_mfma<<<dim3(kB * 11 * 2), 512, 0, stream>>>(ra, rb, box, W0s, b0v, W1, scores);
    k5_softmax<<<kBN, 64, 0, stream>>>(scores, box, att, abox);
    k6_output<<<kBN, 256, 0, stream>>>(obj, fusedbf, ra, rb, att, box, abox, Wba, Wbb, out);
}

// Round 9
// 622.898 us; speedup vs baseline: 1.0569x; 1.0367x over previous
//
#include <hip/hip_runtime.h>
#include <hip/hip_bf16.h>
#include <math.h>

constexpr int kB    = 64;
constexpr int kN    = 36;
constexpr int kBN   = kB * kN;   // 2304
constexpr int kD    = 2048;
constexpr int kDatt = 512;
constexpr int kPairs = kN * kN;  // 1296

using bf16x8 = __attribute__((ext_vector_type(8))) short;
using f32x4  = __attribute__((ext_vector_type(4))) float;

typedef unsigned int u32;
typedef __attribute__((address_space(3))) u32 lds_u32;
typedef const __attribute__((address_space(1))) u32 glb_u32;

// Tiled-permuted bf16 layout (one scheme everywhere, validated as W0s since v5):
//   buf[kb][chunk][512 shorts], kb = k>>5, chunk = row>>4.
//   Granule g (16B) of a chunk holds row (g&7)+((g>>5)<<3), k-granule (g>>3)&3.
//   Element (row,k): g = (rl&7)|(kg<<3)|((rl>>3)<<5), rl=row&15, kg=(k>>3)&3.
//   DMA: 1024 B linear per chunk. Fragment read offset (fr,fq):
//   ((fr&7)<<3)|(fq<<6)|((fr>>3)<<8)  -> all 32 banks 2-way (free).

__device__ inline unsigned short f2bf(float f) {
    union { float f; unsigned u; } v; v.f = f;
    unsigned r = v.u + 0x7FFFu + ((v.u >> 16) & 1u);   // RNE
    return (unsigned short)(r >> 16);
}

// ---------------------------------------------------------------------------
// kcvt_t: f32 [2304][2048] -> bf16 tiled-permuted (nch=144)
// ---------------------------------------------------------------------------
__global__ __launch_bounds__(256)
void kcvt_t(const float* __restrict__ x, unsigned short* __restrict__ y)
{
    int i = blockIdx.x * 256 + threadIdx.x;          // float4 index
    if (i >= kBN * (kD / 4)) return;
    float4 v = ((const float4*)x)[i];
    ushort4 o = {f2bf(v.x), f2bf(v.y), f2bf(v.z), f2bf(v.w)};
    int row = i >> 9;
    int kf  = (i & 511) << 2;
    int kb = kf >> 5;
    int chunk = row >> 4, rl = row & 15;
    int g = (rl & 7) | (((kf >> 3) & 3) << 3) | ((rl >> 3) << 5);
    *(ushort4*)&y[(size_t)kb * (144 * 512) + chunk * 512 + g * 8 + (kf & 7)] = o;
}

// ---------------------------------------------------------------------------
// kzero
// ---------------------------------------------------------------------------
__global__ __launch_bounds__(256)
void kzero(float* __restrict__ p, int n)
{
    int i = blockIdx.x * 256 + threadIdx.x;
    if (i < n) p[i] = 0.f;
}

// ---------------------------------------------------------------------------
// ktrp (plain): W[kD][nt] f32 -> WT[nt][kD] bf16 row-major (used for W0 only)
// ---------------------------------------------------------------------------
__global__ __launch_bounds__(256)
void ktrp(const float* __restrict__ W, unsigned short* __restrict__ WT, int nt)
{
    __shared__ float T[64][65];
    const int k0 = blockIdx.x * 64;
    const int n0 = blockIdx.y * 64;
    const int c = threadIdx.x & 63, r0 = threadIdx.x >> 6;
    #pragma unroll
    for (int rr = 0; rr < 64; rr += 4)
        T[r0 + rr][c] = W[(size_t)(k0 + r0 + rr) * nt + n0 + c];
    __syncthreads();
    #pragma unroll
    for (int rr = 0; rr < 64; rr += 4)
        WT[(size_t)(n0 + r0 + rr) * kD + k0 + c] = f2bf(T[c][r0 + rr]);
}

// ---------------------------------------------------------------------------
// ktrp_t: W[kD][kD] f32 -> tiled-permuted bf16 (nch=128), for Wq/Wo/Wfa/Wfb
// ---------------------------------------------------------------------------
__global__ __launch_bounds__(256)
void ktrp_t(const float* __restrict__ W, unsigned short* __restrict__ Wt)
{
    __shared__ float T[64][65];
    const int k0 = blockIdx.x * 64;
    const int n0 = blockIdx.y * 64;
    const int c = threadIdx.x & 63, r0 = threadIdx.x >> 6;
    #pragma unroll
    for (int rr = 0; rr < 64; rr += 4)
        T[r0 + rr][c] = W[(size_t)(k0 + r0 + rr) * kD + n0 + c];
    __syncthreads();
    #pragma unroll
    for (int rr = 0; rr < 64; rr += 4) {
        int row = n0 + r0 + rr;                 // output row (weight col)
        int k   = k0 + c;
        int kb = k >> 5, kl = k & 31;
        int chunk = row >> 4, rl = row & 15;
        int g = (rl & 7) | (((kl >> 3) & 3) << 3) | ((rl >> 3) << 5);
        Wt[(size_t)kb * (128 * 512) + chunk * 512 + g * 8 + (kl & 7)] = f2bf(T[c][r0 + rr]);
    }
}

// ---------------------------------------------------------------------------
// krepack_w0: W0T[col][k] bf16 row-major -> W0s tiled-permuted (nch=32)
// ---------------------------------------------------------------------------
__global__ __launch_bounds__(64)
void krepack_w0(const unsigned short* __restrict__ W0T, unsigned short* __restrict__ W0s)
{
    const int kb    = blockIdx.x;   // 0..63
    const int chunk = blockIdx.y;   // 0..31
    const int g     = threadIdx.x;  // 0..63
    const int row = chunk * 16 + (g & 7) + ((g >> 5) << 3);
    const int cg8 = ((g >> 3) & 3) * 8;
    const uint4 v = *(const uint4*)&W0T[(size_t)row * kD + kb * 32 + cg8];
    *(uint4*)&W0s[(size_t)kb * 16384 + chunk * 512 + g * 8] = v;
}

// ---------------------------------------------------------------------------
// kgbox (parallel): Gpart[kc][uv][c] = sum_{k in chunk kc} Wba[u,k]Wbb[v,k]W0[k,c]
// ---------------------------------------------------------------------------
__global__ __launch_bounds__(256)
void kgbox(const float* __restrict__ Wba, const float* __restrict__ Wbb,
           const float* __restrict__ W0, float* __restrict__ Gpart)
{
    __shared__ float red[4][64][17];
    const int ct = blockIdx.x;            // 0..7
    const int kc = blockIdx.y;            // 0..15
    const int cl = threadIdx.x & 63;
    const int kq = threadIdx.x >> 6;      // 0..3
    const int c  = ct * 64 + cl;

    float acc[16];
    #pragma unroll
    for (int t = 0; t < 16; ++t) acc[t] = 0.f;

    const int kbase = kc * 128 + kq * 32;
    for (int kk = 0; kk < 32; ++kk) {
        int k = kbase + kk;
        float w0 = W0[(size_t)k * kDatt + c];
        float a0 = Wba[k], a1 = Wba[kD + k], a2 = Wba[2 * kD + k], a3 = Wba[3 * kD + k];
        float b0 = Wbb[k] * w0, b1 = Wbb[kD + k] * w0,
              b2 = Wbb[2 * kD + k] * w0, b3 = Wbb[3 * kD + k] * w0;
        acc[0]  = fmaf(a0, b0, acc[0]);  acc[1]  = fmaf(a0, b1, acc[1]);
        acc[2]  = fmaf(a0, b2, acc[2]);  acc[3]  = fmaf(a0, b3, acc[3]);
        acc[4]  = fmaf(a1, b0, acc[4]);  acc[5]  = fmaf(a1, b1, acc[5]);
        acc[6]  = fmaf(a1, b2, acc[6]);  acc[7]  = fmaf(a1, b3, acc[7]);
        acc[8]  = fmaf(a2, b0, acc[8]);  acc[9]  = fmaf(a2, b1, acc[9]);
        acc[10] = fmaf(a2, b2, acc[10]); acc[11] = fmaf(a2, b3, acc[11]);
        acc[12] = fmaf(a3, b0, acc[12]); acc[13] = fmaf(a3, b1, acc[13]);
        acc[14] = fmaf(a3, b2, acc[14]); acc[15] = fmaf(a3, b3, acc[15]);
    }
    #pragma unroll
    for (int t = 0; t < 16; ++t) red[kq][cl][t] = acc[t];
    __syncthreads();
    #pragma unroll
    for (int t = 0; t < 4; ++t) {
        int s = threadIdx.x + t * 256;
        int cc = s >> 4, uv = s & 15;
        float v = red[0][cc][uv] + red[1][cc][uv] + red[2][cc][uv] + red[3][cc][uv];
        Gpart[((size_t)kc * 16 + uv) * kDatt + ct * 64 + cc] = v;
    }
}

// ---------------------------------------------------------------------------
// krepack_g: sum 16 partials -> W0s K-block 64 (bf16, permuted, zero-pad 16..31)
// ---------------------------------------------------------------------------
__global__ __launch_bounds__(64)
void krepack_g(const float* __restrict__ Gpart, unsigned short* __restrict__ W0s)
{
    const int chunk = blockIdx.x;   // 0..31
    const int g     = threadIdx.x;  // 0..63
    const int col = chunk * 16 + (g & 7) + ((g >> 5) << 3);
    const int kg  = (g >> 3) & 3;
    unsigned short o[8];
    #pragma unroll
    for (int e = 0; e < 8; ++e) {
        int kl = kg * 8 + e;
        if (kl < 16) {
            float s = 0.f;
            #pragma unroll
            for (int kc = 0; kc < 16; ++kc)
                s += Gpart[((size_t)kc * 16 + kl) * kDatt + col];
            o[e] = f2bf(s);
        } else o[e] = 0;
    }
    *(uint4*)&W0s[(size_t)64 * 16384 + chunk * 512 + g * 8] = *(uint4*)o;
}

// ---------------------------------------------------------------------------
// K1 v12: conflict-free via tiled-permuted operands. 128x64 tile, 4 waves,
// wave tile 64x32 per GEMM. All fragment reads hit 32 banks 2-way; all DMA
// linear 1024 B. fused written tiled-permuted (k2's A operand).
// ---------------------------------------------------------------------------
__global__ __launch_bounds__(256, 2)
void k1_dual_mfma(const unsigned short* __restrict__ Qt,
                  const unsigned short* __restrict__ Wqt,
                  const unsigned short* __restrict__ Ot,
                  const unsigned short* __restrict__ Wot,
                  unsigned short* __restrict__ fusedt)
{
    __shared__ __align__(16) unsigned short As1[128 * 32];
    __shared__ __align__(16) unsigned short As2[128 * 32];
    __shared__ __align__(16) unsigned short Bs1[64 * 32];
    __shared__ __align__(16) unsigned short Bs2[64 * 32];

    const int tid = threadIdx.x;
    const int lane = tid & 63;
    const int w = tid >> 6;            // 0..3
    const int wm = w >> 1, wn = w & 1;
    const int row0 = blockIdx.y * 128;
    const int col0 = blockIdx.x * 64;
    const int chA = row0 >> 4;
    const int chB = col0 >> 4;

    f32x4 acc1[4][2], acc2[4][2];
    #pragma unroll
    for (int mt = 0; mt < 4; ++mt)
        #pragma unroll
        for (int nt = 0; nt < 2; ++nt) { acc1[mt][nt] = (f32x4)(0.f); acc2[mt][nt] = (f32x4)(0.f); }

    const int fr = lane & 15, fq = lane >> 4;
    const int inoff = ((fr & 7) << 3) | (fq << 6) | ((fr >> 3) << 8);

    for (int kb = 0; kb < 64; ++kb) {
        #pragma unroll
        for (int t = 0; t < 2; ++t) {
            int cl = w * 2 + t;
            __builtin_amdgcn_global_load_lds((glb_u32*)(Qt + ((size_t)kb * 144 + chA + cl) * 512 + lane * 8),
                                             (lds_u32*)&As1[cl * 512], 16, 0, 0);
            __builtin_amdgcn_global_load_lds((glb_u32*)(Ot + ((size_t)kb * 144 + chA + cl) * 512 + lane * 8),
                                             (lds_u32*)&As2[cl * 512], 16, 0, 0);
        }
        __builtin_amdgcn_global_load_lds((glb_u32*)(Wqt + ((size_t)kb * 128 + chB + w) * 512 + lane * 8),
                                         (lds_u32*)&Bs1[w * 512], 16, 0, 0);
        __builtin_amdgcn_global_load_lds((glb_u32*)(Wot + ((size_t)kb * 128 + chB + w) * 512 + lane * 8),
                                         (lds_u32*)&Bs2[w * 512], 16, 0, 0);
        __syncthreads();

        bf16x8 a1[4], a2[4];
        #pragma unroll
        for (int mt = 0; mt < 4; ++mt) {
            a1[mt] = *(bf16x8*)&As1[(wm * 4 + mt) * 512 + inoff];
            a2[mt] = *(bf16x8*)&As2[(wm * 4 + mt) * 512 + inoff];
        }
        #pragma unroll
        for (int nt = 0; nt < 2; ++nt) {
            bf16x8 b1 = *(bf16x8*)&Bs1[(wn * 2 + nt) * 512 + inoff];
            bf16x8 b2 = *(bf16x8*)&Bs2[(wn * 2 + nt) * 512 + inoff];
            #pragma unroll
            for (int mt = 0; mt < 4; ++mt) {
                acc1[mt][nt] = __builtin_amdgcn_mfma_f32_16x16x32_bf16(a1[mt], b1, acc1[mt][nt], 0, 0, 0);
                acc2[mt][nt] = __builtin_amdgcn_mfma_f32_16x16x32_bf16(a2[mt], b2, acc2[mt][nt], 0, 0, 0);
            }
        }
        __syncthreads();
    }

    #pragma unroll
    for (int mt = 0; mt < 4; ++mt)
        #pragma unroll
        for (int nt = 0; nt < 2; ++nt) {
            #pragma unroll
            for (int reg = 0; reg < 4; ++reg) {
                int row = row0 + wm * 64 + mt * 16 + fq * 4 + reg;
                int col = col0 + wn * 32 + nt * 16 + fr;
                float v = acc1[mt][nt][reg] * acc2[mt][nt][reg];
                int kbo = col >> 5, kl = col & 31;
                int chunk = row >> 4, rl = row & 15;
                int g = (rl & 7) | (((kl >> 3) & 3) << 3) | ((rl >> 3) << 5);
                fusedt[(size_t)kbo * (144 * 512) + chunk * 512 + g * 8 + (kl & 7)] = f2bf(v);
            }
        }
}

// ---------------------------------------------------------------------------
// K2 v12: same conflict-free structure; ra/rb written f32 row-major.
// ---------------------------------------------------------------------------
__global__ __launch_bounds__(256, 2)
void k2_dual_mfma(const unsigned short* __restrict__ Ft,
                  const unsigned short* __restrict__ Wfat,
                  const unsigned short* __restrict__ Wfbt,
                  float* __restrict__ ra, float* __restrict__ rb)
{
    __shared__ __align__(16) unsigned short As [128 * 32];
    __shared__ __align__(16) unsigned short Bs1[64 * 32];
    __shared__ __align__(16) unsigned short Bs2[64 * 32];

    const int tid = threadIdx.x;
    const int lane = tid & 63;
    const int w = tid >> 6;
    const int wm = w >> 1, wn = w & 1;
    const int row0 = blockIdx.y * 128;
    const int col0 = blockIdx.x * 64;
    const int chA = row0 >> 4;
    const int chB = col0 >> 4;

    f32x4 acc1[4][2], acc2[4][2];
    #pragma unroll
    for (int mt = 0; mt < 4; ++mt)
        #pragma unroll
        for (int nt = 0; nt < 2; ++nt) { acc1[mt][nt] = (f32x4)(0.f); acc2[mt][nt] = (f32x4)(0.f); }

    const int fr = lane & 15, fq = lane >> 4;
    const int inoff = ((fr & 7) << 3) | (fq << 6) | ((fr >> 3) << 8);

    for (int kb = 0; kb < 64; ++kb) {
        #pragma unroll
        for (int t = 0; t < 2; ++t) {
            int cl = w * 2 + t;
            __builtin_amdgcn_global_load_lds((glb_u32*)(Ft + ((size_t)kb * 144 + chA + cl) * 512 + lane * 8),
                                             (lds_u32*)&As[cl * 512], 16, 0, 0);
        }
        __builtin_amdgcn_global_load_lds((glb_u32*)(Wfat + ((size_t)kb * 128 + chB + w) * 512 + lane * 8),
                                         (lds_u32*)&Bs1[w * 512], 16, 0, 0);
        __builtin_amdgcn_global_load_lds((glb_u32*)(Wfbt + ((size_t)kb * 128 + chB + w) * 512 + lane * 8),
                                         (lds_u32*)&Bs2[w * 512], 16, 0, 0);
        __syncthreads();

        bf16x8 a[4];
        #pragma unroll
        for (int mt = 0; mt < 4; ++mt)
            a[mt] = *(bf16x8*)&As[(wm * 4 + mt) * 512 + inoff];
        #pragma unroll
        for (int nt = 0; nt < 2; ++nt) {
            bf16x8 b1 = *(bf16x8*)&Bs1[(wn * 2 + nt) * 512 + inoff];
            bf16x8 b2 = *(bf16x8*)&Bs2[(wn * 2 + nt) * 512 + inoff];
            #pragma unroll
            for (int mt = 0; mt < 4; ++mt) {
                acc1[mt][nt] = __builtin_amdgcn_mfma_f32_16x16x32_bf16(a[mt], b1, acc1[mt][nt], 0, 0, 0);
                acc2[mt][nt] = __builtin_amdgcn_mfma_f32_16x16x32_bf16(a[mt], b2, acc2[mt][nt], 0, 0, 0);
            }
        }
        __syncthreads();
    }

    #pragma unroll
    for (int mt = 0; mt < 4; ++mt)
        #pragma unroll
        for (int nt = 0; nt < 2; ++nt) {
            int row = row0 + wm * 64 + mt * 16 + fq * 4;
            int col = col0 + wn * 32 + nt * 16 + fr;
            #pragma unroll
            for (int reg = 0; reg < 4; ++reg) {
                size_t o = (size_t)(row + reg) * kD + col;
                ra[o] = acc1[mt][nt][reg];
                rb[o] = acc2[mt][nt][reg];
            }
        }
}

// ---------------------------------------------------------------------------
// K4 v11 (unchanged): N-split, 2 blocks/CU; box folded as K-step 64.
// ---------------------------------------------------------------------------
__global__ __launch_bounds__(512, 4)
void k4_scores_mfma(const float* __restrict__ ra, const float* __restrict__ rb,
                    const float* __restrict__ box,
                    const unsigned short* __restrict__ W0s,
                    const float* __restrict__ b0, const float* __restrict__ W1,
                    float* __restrict__ scores)
{
    __shared__ __align__(16) unsigned short Bs[2][256 * 32];  // 32 KB
    __shared__ __align__(16) unsigned short RelS[2][128][40]; // 20 KB
    __shared__ __align__(16) float4 Stg4[2][378];             // 12 KB
    __shared__ float scoreS[128];

    const int tid  = threadIdx.x;
    const int lane = tid & 63;
    const int w    = tid >> 6;        // 0..7
    const int wm   = w >> 2;
    const int wn   = w & 3;

    const int work = (blockIdx.x & 7) * 176 + (blockIdx.x >> 3);
    const int colb = work & 1;
    const int wt   = work >> 1;
    const int b    = wt / 11;
    const int tile = wt - b * 11;
    const int p0   = tile * 128;
    const int i0   = p0 / kN;

    const float* raB  = ra  + (size_t)b * kN * kD;
    const float* rbB  = rb  + (size_t)b * kN * kD;
    const float* boxB = box + (size_t)b * kN * 4;

    const bool hasStage = (tid < 336);
    const float* sptr;
    int sdst;
    {
        int s = hasStage ? tid : 335;
        int row = s >> 3, q = s & 7;
        int grow; const float* base;
        if (row < 6) {
            int il = (row < 5) ? row : 4;
            grow = i0 + il; if (grow > kN - 1) grow = kN - 1;
            base = raB;
        } else {
            grow = row - 6;
            base = rbB;
        }
        sptr = base + (size_t)grow * kD + q * 4;
        sdst = row * 9 + q;
    }

    int rowA, cg2, iA, jA, sA, sR;
    {
        rowA = tid >> 2; cg2 = tid & 3;
        int p = p0 + rowA; if (p >= kPairs) p = kPairs - 1;
        iA = p / kN;
        jA = p - iA * kN;
        int ilA = iA - i0;
        sA = ilA * 9 + cg2 * 2;
        sR = (6 + jA) * 9 + cg2 * 2;
    }

    const int fr = lane & 15, fq = lane >> 4;
    const int bco = ((fr & 7) << 3) + ((fr >> 3) << 8) + (fq << 6);

    f32x4 acc[4][4];
    #pragma unroll
    for (int mt = 0; mt < 4; ++mt)
        #pragma unroll
        for (int nt = 0; nt < 4; ++nt)
            acc[mt][nt] = (f32x4)(0.f);

    if (tid < 128) scoreS[tid] = 0.f;

    float4 sreg0;

    #define ISSUE_B(k0_, buf_)                                                   \
        _Pragma("unroll")                                                        \
        for (int t = 0; t < 2; ++t) {                                            \
            int ch = w * 2 + t;                                                  \
            const unsigned short* gp = W0s + (size_t)((k0_) >> 5) * 16384        \
                                       + (colb * 16 + ch) * 512 + lane * 8;      \
            __builtin_amdgcn_global_load_lds((glb_u32*)gp,                       \
                (lds_u32*)&Bs[buf_][ch * 512], 16, 0, 0);                        \
        }

    #define STAGE_LOAD(k0_) {                                                    \
            if (hasStage) sreg0 = *(const float4*)(sptr + (k0_));                \
        }

    #define STAGE_WRITE(buf_) {                                                  \
            if (hasStage) Stg4[buf_][sdst] = sreg0;                              \
        }

    #define REL_GEN(buf_) {                                                      \
            float4 va0 = Stg4[buf_][sA],     va1 = Stg4[buf_][sA + 1];           \
            float4 vr0 = Stg4[buf_][sR],     vr1 = Stg4[buf_][sR + 1];           \
            unsigned short o[8];                                                 \
            o[0] = f2bf(va0.x * vr0.x); o[1] = f2bf(va0.y * vr0.y);              \
            o[2] = f2bf(va0.z * vr0.z); o[3] = f2bf(va0.w * vr0.w);              \
            o[4] = f2bf(va1.x * vr1.x); o[5] = f2bf(va1.y * vr1.y);              \
            o[6] = f2bf(va1.z * vr1.z); o[7] = f2bf(va1.w * vr1.w);              \
            *(bf16x8*)&RelS[buf_][rowA][cg2 * 8] = *(bf16x8*)o;                  \
        }

    #define REL_GEN_BOX(buf_) {                                                  \
            unsigned short o[8] = {0, 0, 0, 0, 0, 0, 0, 0};                      \
            if (cg2 < 2) {                                                       \
                float4 bj = *(const float4*)(boxB + jA * 4);                     \
                float biu0 = boxB[iA * 4 + cg2 * 2];                             \
                float biu1 = boxB[iA * 4 + cg2 * 2 + 1];                         \
                o[0] = f2bf(biu0 * bj.x); o[1] = f2bf(biu0 * bj.y);              \
                o[2] = f2bf(biu0 * bj.z); o[3] = f2bf(biu0 * bj.w);              \
                o[4] = f2bf(biu1 * bj.x); o[5] = f2bf(biu1 * bj.y);              \
                o[6] = f2bf(biu1 * bj.z); o[7] = f2bf(biu1 * bj.w);              \
            }                                                                    \
            *(bf16x8*)&RelS[buf_][rowA][cg2 * 8] = *(bf16x8*)o;                  \
        }

    STAGE_LOAD(0)
    STAGE_WRITE(0)
    STAGE_LOAD(32)
    __syncthreads();
    REL_GEN(0)
    STAGE_WRITE(1)
    ISSUE_B(0, 0)

    for (int k = 0; k <= 64; ++k) {
        const int cur = k & 1, nxt = cur ^ 1;
        __syncthreads();
        if (k < 62) STAGE_LOAD((k + 2) * 32)
        if (k < 64) ISSUE_B((k + 1) * 32, nxt)
        bf16x8 af[4];
        #pragma unroll
        for (int mt = 0; mt < 4; ++mt)
            af[mt] = *(bf16x8*)&RelS[cur][wm * 64 + mt * 16 + fr][fq * 8];
        if (k < 63) REL_GEN(nxt)
        else if (k == 63) REL_GEN_BOX(nxt)
        __builtin_amdgcn_s_setprio(1);
        #pragma unroll
        for (int nt = 0; nt < 4; ++nt) {
            bf16x8 bfv = *(bf16x8*)&Bs[cur][wn * 2048 + nt * 512 + bco];
            #pragma unroll
            for (int mt = 0; mt < 4; ++mt)
                acc[mt][nt] = __builtin_amdgcn_mfma_f32_16x16x32_bf16(af[mt], bfv, acc[mt][nt], 0, 0, 0);
        }
        __builtin_amdgcn_s_setprio(0);
        if (k < 62) STAGE_WRITE(cur)
    }

    float b0v[4], w1v[4];
    #pragma unroll
    for (int nt = 0; nt < 4; ++nt) {
        int col = colb * 256 + wn * 64 + nt * 16 + fr;
        b0v[nt] = b0[col];
        w1v[nt] = W1[col];
    }
    #pragma unroll
    for (int mt = 0; mt < 4; ++mt) {
        #pragma unroll
        for (int reg = 0; reg < 4; ++reg) {
            float p = 0.f;
            #pragma unroll
            for (int nt = 0; nt < 4; ++nt)
                p += w1v[nt] * tanhf(acc[mt][nt][reg] + b0v[nt]);
            p += __shfl_xor(p, 1, 64);
            p += __shfl_xor(p, 2, 64);
            p += __shfl_xor(p, 4, 64);
            p += __shfl_xor(p, 8, 64);
            if (fr == 0)
                atomicAdd(&scoreS[wm * 64 + mt * 16 + fq * 4 + reg], p);
        }
    }
    __syncthreads();
    if (tid < 128 && p0 + tid < kPairs)
        atomicAdd(&scores[(size_t)b * kPairs + p0 + tid], scoreS[tid]);
}

// ---------------------------------------------------------------------------
// K5: softmax over j + abox[bi,:] = sum_j att[bi,j] * box[b,j,:]
// ---------------------------------------------------------------------------
__global__ __launch_bounds__(64)
void k5_softmax(const float* __restrict__ scores, const float* __restrict__ box,
                float* __restrict__ att, float* __restrict__ abox)
{
    const int bi = blockIdx.x;
    const int b  = bi / kN;
    const int tid = threadIdx.x;
    float s = (tid < kN) ? scores[(size_t)bi * kN + tid] : -1e30f;
    float m = s;
    #pragma unroll
    for (int off = 32; off >= 1; off >>= 1)
        m = fmaxf(m, __shfl_xor(m, off, 64));
    float e = (tid < kN) ? expf(s - m) : 0.f;
    float sum = e;
    #pragma unroll
    for (int off = 32; off >= 1; off >>= 1)
        sum += __shfl_xor(sum, off, 64);
    float a = e / sum;
    if (tid < kN) att[(size_t)bi * kN + tid] = a;

    float4 bx = {0.f, 0.f, 0.f, 0.f};
    if (tid < kN) bx = *(const float4*)(box + (size_t)(b * kN + tid) * 4);
    bx.x *= a; bx.y *= a; bx.z *= a; bx.w *= a;
    #pragma unroll
    for (int off = 32; off >= 1; off >>= 1) {
        bx.x += __shfl_xor(bx.x, off, 64);
        bx.y += __shfl_xor(bx.y, off, 64);
        bx.z += __shfl_xor(bx.z, off, 64);
        bx.w += __shfl_xor(bx.w, off, 64);
    }
    if (tid == 0) *(float4*)(abox + (size_t)bi * 4) = bx;
}

// ---------------------------------------------------------------------------
// K6 v12: XCD-chunked swizzle (2304 = 8*288) colocates same-b blocks on one
// XCD so the rb gather (295 KB/b, read by 36 blocks) is L2-resident --
// previously round-robin spread it across XCDs = L3 thrash. fused read is
// tiled-permuted. Rank-4 box term as before.
// ---------------------------------------------------------------------------
__global__ __launch_bounds__(256)
void k6_output(const float* __restrict__ obj, const unsigned short* __restrict__ fusedt,
               const float* __restrict__ ra, const float* __restrict__ rb,
               const float* __restrict__ att, const float* __restrict__ box,
               const float* __restrict__ abox,
               const float* __restrict__ Wba, const float* __restrict__ Wbb,
               float* __restrict__ out)
{
    __shared__ float attS[kN];
    const int bi = (blockIdx.x & 7) * 288 + (blockIdx.x >> 3);  // XCD swizzle
    const int b = bi / kN;
    const int tid = threadIdx.x;
    if (tid < kN) attS[tid] = att[(size_t)bi * kN + tid];
    __syncthreads();
    const float4 bxi = *(const float4*)(box  + (size_t)bi * 4);
    const float4 axi = *(const float4*)(abox + (size_t)bi * 4);
    const int chunk = bi >> 4, rl = bi & 15;
    for (int d = tid; d < kD; d += 256) {
        float s1 = 0.f;
        #pragma unroll 4
        for (int j = 0; j < kN; ++j)
            s1 = fmaf(attS[j], rb[(size_t)(b * kN + j) * kD + d], s1);
        float bav = bxi.x * Wba[d] + bxi.y * Wba[kD + d]
                  + bxi.z * Wba[2 * kD + d] + bxi.w * Wba[3 * kD + d];
        float s2  = axi.x * Wbb[d] + axi.y * Wbb[kD + d]
                  + axi.z * Wbb[2 * kD + d] + axi.w * Wbb[3 * kD + d];
        size_t o = (size_t)bi * kD + d;
        int kbf = d >> 5, klf = d & 31;
        int g = (rl & 7) | (((klf >> 3) & 3) << 3) | ((rl >> 3) << 5);
        float fv = __uint_as_float(
            (u32)fusedt[(size_t)kbf * (144 * 512) + chunk * 512 + g * 8 + (klf & 7)] << 16);
        out[o] = obj[o] + fv + ra[o] * s1 + bav * s2;
    }
}

// ---------------------------------------------------------------------------
extern "C" void kernel_launch(void* const* d_in, const int* in_sizes, int n_in,
                              void* d_out, int out_size, void* d_ws, size_t ws_size,
                              hipStream_t stream)
{
    const float* q   = (const float*)d_in[0];
    const float* obj = (const float*)d_in[1];
    const float* box = (const float*)d_in[2];
    const float* Wq  = (const float*)d_in[3];
    const float* Wo  = (const float*)d_in[4];
    const float* Wfa = (const float*)d_in[5];
    const float* Wfb = (const float*)d_in[6];
    const float* Wba = (const float*)d_in[7];
    const float* Wbb = (const float*)d_in[8];
    const float* W0  = (const float*)d_in[9];
    const float* b0v = (const float*)d_in[10];
    const float* W1  = (const float*)d_in[11];
    float* out = (float*)d_out;

    const size_t nBD = (size_t)kBN * kD;
    float* ws = (float*)d_ws;
    size_t off = 0;
    float* ra     = ws + off; off += nBD;
    float* rb     = ws + off; off += nBD;
    float* scores = ws + off; off += (size_t)kBN * kN;
    float* att    = ws + off; off += (size_t)kBN * kN;
    float* abox   = ws + off; off += (size_t)kBN * 4;
    float* Gpart  = ws + off; off += (size_t)16 * 16 * kDatt;

    unsigned short* us = (unsigned short*)(ws + off);
    size_t uoff = 0;
    unsigned short* W0T    = us + uoff; uoff += (size_t)kDatt * kD;
    unsigned short* W0s    = us + uoff; uoff += (size_t)65 * 16384;
    unsigned short* qt     = us + uoff; uoff += nBD;           // tiled act
    unsigned short* objt   = us + uoff; uoff += nBD;           // tiled act
    unsigned short* fusedt = us + uoff; uoff += nBD;           // tiled act
    unsigned short* Wqt    = us + uoff; uoff += (size_t)kD * kD;
    unsigned short* Wot    = us + uoff; uoff += (size_t)kD * kD;
    // Wfat/Wfbt alias qt/objt (dead after k1; stream order guarantees safety)
    unsigned short* Wfat = qt;
    unsigned short* Wfbt = objt;

    kcvt_t<<<dim3(kBN * (kD / 4) / 256), 256, 0, stream>>>(q,   qt);
    kcvt_t<<<dim3(kBN * (kD / 4) / 256), 256, 0, stream>>>(obj, objt);
    ktrp<<<dim3(32, 8), 256, 0, stream>>>(W0, W0T, kDatt);
    krepack_w0<<<dim3(64, 32), 64, 0, stream>>>(W0T, W0s);
    kgbox<<<dim3(8, 16), 256, 0, stream>>>(Wba, Wbb, W0, Gpart);
    krepack_g<<<dim3(32), 64, 0, stream>>>(Gpart, W0s);
    kzero<<<dim3((kBN * kN + 255) / 256), 256, 0, stream>>>(scores, kBN * kN);
    ktrp_t<<<dim3(32, 32), 256, 0, stream>>>(Wq, Wqt);
    ktrp_t<<<dim3(32, 32), 256, 0, stream>>>(Wo, Wot);

    k1_dual_mfma<<<dim3(kD / 64, kBN / 128), 256, 0, stream>>>(qt, Wqt, objt, Wot, fusedt);

    ktrp_t<<<dim3(32, 32), 256, 0, stream>>>(Wfa, Wfat);
    ktrp_t<<<dim3(32, 32), 256, 0, stream>>>(Wfb, Wfbt);

    k2_dual_mfma<<<dim3(kD / 64, kBN / 128), 256, 0, stream>>>(fusedt, Wfat, Wfbt, ra, rb);

    k4_scores_mfma<<<dim3(kB * 11 * 2), 512, 0, stream>>>(ra, rb, box, W0s, b0v, W1, scores);
    k5_softmax<<<kBN, 64, 0, stream>>>(scores, box, att, abox);
    k6_output<<<kBN, 256, 0, stream>>>(obj, fusedt, ra, rb, att, box, abox, Wba, Wbb, out);
}

// Round 10
// 613.357 us; speedup vs baseline: 1.0733x; 1.0156x over previous
//
#include <hip/hip_runtime.h>
#include <hip/hip_bf16.h>
#include <math.h>

constexpr int kB    = 64;
constexpr int kN    = 36;
constexpr int kBN   = kB * kN;   // 2304
constexpr int kD    = 2048;
constexpr int kDatt = 512;
constexpr int kPairs = kN * kN;  // 1296

using bf16x8 = __attribute__((ext_vector_type(8))) short;
using f32x4  = __attribute__((ext_vector_type(4))) float;

typedef unsigned int u32;
typedef __attribute__((address_space(3))) u32 lds_u32;
typedef const __attribute__((address_space(1))) u32 glb_u32;

// Tiled-permuted bf16 layout (validated since v5 as W0s):
//   buf[kb][chunk][512 shorts], kb = k>>5, chunk = row>>4.
//   Granule g (16B) holds row (g&7)+((g>>5)<<3), k-granule (g>>3)&3.
//   Element (row,k): g = (rl&7)|(((k>>3)&3)<<3)|((rl>>3)<<5), rl=row&15.
//   Fragment read offset for (fr,fq): ((fr&7)<<3)|(fq<<6)|((fr>>3)<<8)
//   -> one wave's fragment = exactly one 1KB chunk (coalesced / 2-way banks).

__device__ inline unsigned short f2bf(float f) {
    union { float f; unsigned u; } v; v.f = f;
    unsigned r = v.u + 0x7FFFu + ((v.u >> 16) & 1u);   // RNE
    return (unsigned short)(r >> 16);
}

// ---------------------------------------------------------------------------
// kcvt2: q and obj f32 -> bf16 tiled-permuted (nch=144), fused (blockIdx.y)
// ---------------------------------------------------------------------------
__global__ __launch_bounds__(256)
void kcvt2(const float* __restrict__ q, const float* __restrict__ obj,
           unsigned short* __restrict__ qt, unsigned short* __restrict__ objt)
{
    const float* x = blockIdx.y ? obj : q;
    unsigned short* y = blockIdx.y ? objt : qt;
    int i = blockIdx.x * 256 + threadIdx.x;          // float4 index
    if (i >= kBN * (kD / 4)) return;
    float4 v = ((const float4*)x)[i];
    ushort4 o = {f2bf(v.x), f2bf(v.y), f2bf(v.z), f2bf(v.w)};
    int row = i >> 9;
    int kf  = (i & 511) << 2;
    int kb = kf >> 5;
    int chunk = row >> 4, rl = row & 15;
    int g = (rl & 7) | (((kf >> 3) & 3) << 3) | ((rl >> 3) << 5);
    *(ushort4*)&y[(size_t)kb * (144 * 512) + chunk * 512 + g * 8 + (kf & 7)] = o;
}

// ---------------------------------------------------------------------------
// kzero
// ---------------------------------------------------------------------------
__global__ __launch_bounds__(256)
void kzero(float* __restrict__ p, int n)
{
    int i = blockIdx.x * 256 + threadIdx.x;
    if (i < n) p[i] = 0.f;
}

// ---------------------------------------------------------------------------
// ktrp5: all 5 weight transposes fused (blockIdx.z selects matrix).
// W[kD][nt] f32 -> tiled-permuted bf16 (nch = nt/16). W0 (nt=512) writes
// W0s blocks 0..63 directly (krepack_g fills block 64).
// ---------------------------------------------------------------------------
__global__ __launch_bounds__(256)
void ktrp5(const float* __restrict__ Wq, const float* __restrict__ Wo,
           const float* __restrict__ Wfa, const float* __restrict__ Wfb,
           const float* __restrict__ W0,
           unsigned short* __restrict__ Wqt, unsigned short* __restrict__ Wot,
           unsigned short* __restrict__ Wfat, unsigned short* __restrict__ Wfbt,
           unsigned short* __restrict__ W0s)
{
    const int z = blockIdx.z;
    const float* W; unsigned short* Wt; int nt;
    if      (z == 0) { W = Wq;  Wt = Wqt;  nt = kD; }
    else if (z == 1) { W = Wo;  Wt = Wot;  nt = kD; }
    else if (z == 2) { W = Wfa; Wt = Wfat; nt = kD; }
    else if (z == 3) { W = Wfb; Wt = Wfbt; nt = kD; }
    else             { W = W0;  Wt = W0s;  nt = kDatt; }
    const int n0 = blockIdx.y * 64;
    if (n0 >= nt) return;                 // uniform early-exit (W0: y<8)
    const int nch = nt >> 4;
    const int k0 = blockIdx.x * 64;
    __shared__ float T[64][65];
    const int c = threadIdx.x & 63, r0 = threadIdx.x >> 6;
    #pragma unroll
    for (int rr = 0; rr < 64; rr += 4)
        T[r0 + rr][c] = W[(size_t)(k0 + r0 + rr) * nt + n0 + c];
    __syncthreads();
    #pragma unroll
    for (int rr = 0; rr < 64; rr += 4) {
        int row = n0 + r0 + rr;           // output row (weight col)
        int k   = k0 + c;
        int kb = k >> 5, kl = k & 31;
        int chunk = row >> 4, rl = row & 15;
        int g = (rl & 7) | (((kl >> 3) & 3) << 3) | ((rl >> 3) << 5);
        Wt[(size_t)kb * (nch * 512) + chunk * 512 + g * 8 + (kl & 7)] = f2bf(T[c][r0 + rr]);
    }
}

// ---------------------------------------------------------------------------
// kgbox (parallel): Gpart[kc][uv][c] = sum_{k in chunk kc} Wba[u,k]Wbb[v,k]W0[k,c]
// ---------------------------------------------------------------------------
__global__ __launch_bounds__(256)
void kgbox(const float* __restrict__ Wba, const float* __restrict__ Wbb,
           const float* __restrict__ W0, float* __restrict__ Gpart)
{
    __shared__ float red[4][64][17];
    const int ct = blockIdx.x;            // 0..7
    const int kc = blockIdx.y;            // 0..15
    const int cl = threadIdx.x & 63;
    const int kq = threadIdx.x >> 6;      // 0..3
    const int c  = ct * 64 + cl;

    float acc[16];
    #pragma unroll
    for (int t = 0; t < 16; ++t) acc[t] = 0.f;

    const int kbase = kc * 128 + kq * 32;
    for (int kk = 0; kk < 32; ++kk) {
        int k = kbase + kk;
        float w0 = W0[(size_t)k * kDatt + c];
        float a0 = Wba[k], a1 = Wba[kD + k], a2 = Wba[2 * kD + k], a3 = Wba[3 * kD + k];
        float b0 = Wbb[k] * w0, b1 = Wbb[kD + k] * w0,
              b2 = Wbb[2 * kD + k] * w0, b3 = Wbb[3 * kD + k] * w0;
        acc[0]  = fmaf(a0, b0, acc[0]);  acc[1]  = fmaf(a0, b1, acc[1]);
        acc[2]  = fmaf(a0, b2, acc[2]);  acc[3]  = fmaf(a0, b3, acc[3]);
        acc[4]  = fmaf(a1, b0, acc[4]);  acc[5]  = fmaf(a1, b1, acc[5]);
        acc[6]  = fmaf(a1, b2, acc[6]);  acc[7]  = fmaf(a1, b3, acc[7]);
        acc[8]  = fmaf(a2, b0, acc[8]);  acc[9]  = fmaf(a2, b1, acc[9]);
        acc[10] = fmaf(a2, b2, acc[10]); acc[11] = fmaf(a2, b3, acc[11]);
        acc[12] = fmaf(a3, b0, acc[12]); acc[13] = fmaf(a3, b1, acc[13]);
        acc[14] = fmaf(a3, b2, acc[14]); acc[15] = fmaf(a3, b3, acc[15]);
    }
    #pragma unroll
    for (int t = 0; t < 16; ++t) red[kq][cl][t] = acc[t];
    __syncthreads();
    #pragma unroll
    for (int t = 0; t < 4; ++t) {
        int s = threadIdx.x + t * 256;
        int cc = s >> 4, uv = s & 15;
        float v = red[0][cc][uv] + red[1][cc][uv] + red[2][cc][uv] + red[3][cc][uv];
        Gpart[((size_t)kc * 16 + uv) * kDatt + ct * 64 + cc] = v;
    }
}

// ---------------------------------------------------------------------------
// krepack_g: sum 16 partials -> W0s K-block 64 (bf16, permuted, zero-pad 16..31)
// ---------------------------------------------------------------------------
__global__ __launch_bounds__(64)
void krepack_g(const float* __restrict__ Gpart, unsigned short* __restrict__ W0s)
{
    const int chunk = blockIdx.x;   // 0..31
    const int g     = threadIdx.x;  // 0..63
    const int col = chunk * 16 + (g & 7) + ((g >> 5) << 3);
    const int kg  = (g >> 3) & 3;
    unsigned short o[8];
    #pragma unroll
    for (int e = 0; e < 8; ++e) {
        int kl = kg * 8 + e;
        if (kl < 16) {
            float s = 0.f;
            #pragma unroll
            for (int kc = 0; kc < 16; ++kc)
                s += Gpart[((size_t)kc * 16 + kl) * kDatt + col];
            o[e] = f2bf(s);
        } else o[e] = 0;
    }
    *(uint4*)&W0s[(size_t)64 * 16384 + chunk * 512 + g * 8] = *(uint4*)o;
}

// ---------------------------------------------------------------------------
// K1: conflict-free via tiled-permuted operands (v12 structure unchanged).
// ---------------------------------------------------------------------------
__global__ __launch_bounds__(256, 2)
void k1_dual_mfma(const unsigned short* __restrict__ Qt,
                  const unsigned short* __restrict__ Wqt,
                  const unsigned short* __restrict__ Ot,
                  const unsigned short* __restrict__ Wot,
                  unsigned short* __restrict__ fusedt)
{
    __shared__ __align__(16) unsigned short As1[128 * 32];
    __shared__ __align__(16) unsigned short As2[128 * 32];
    __shared__ __align__(16) unsigned short Bs1[64 * 32];
    __shared__ __align__(16) unsigned short Bs2[64 * 32];

    const int tid = threadIdx.x;
    const int lane = tid & 63;
    const int w = tid >> 6;            // 0..3
    const int wm = w >> 1, wn = w & 1;
    const int row0 = blockIdx.y * 128;
    const int col0 = blockIdx.x * 64;
    const int chA = row0 >> 4;
    const int chB = col0 >> 4;

    f32x4 acc1[4][2], acc2[4][2];
    #pragma unroll
    for (int mt = 0; mt < 4; ++mt)
        #pragma unroll
        for (int nt = 0; nt < 2; ++nt) { acc1[mt][nt] = (f32x4)(0.f); acc2[mt][nt] = (f32x4)(0.f); }

    const int fr = lane & 15, fq = lane >> 4;
    const int inoff = ((fr & 7) << 3) | (fq << 6) | ((fr >> 3) << 8);

    for (int kb = 0; kb < 64; ++kb) {
        #pragma unroll
        for (int t = 0; t < 2; ++t) {
            int cl = w * 2 + t;
            __builtin_amdgcn_global_load_lds((glb_u32*)(Qt + ((size_t)kb * 144 + chA + cl) * 512 + lane * 8),
                                             (lds_u32*)&As1[cl * 512], 16, 0, 0);
            __builtin_amdgcn_global_load_lds((glb_u32*)(Ot + ((size_t)kb * 144 + chA + cl) * 512 + lane * 8),
                                             (lds_u32*)&As2[cl * 512], 16, 0, 0);
        }
        __builtin_amdgcn_global_load_lds((glb_u32*)(Wqt + ((size_t)kb * 128 + chB + w) * 512 + lane * 8),
                                         (lds_u32*)&Bs1[w * 512], 16, 0, 0);
        __builtin_amdgcn_global_load_lds((glb_u32*)(Wot + ((size_t)kb * 128 + chB + w) * 512 + lane * 8),
                                         (lds_u32*)&Bs2[w * 512], 16, 0, 0);
        __syncthreads();

        bf16x8 a1[4], a2[4];
        #pragma unroll
        for (int mt = 0; mt < 4; ++mt) {
            a1[mt] = *(bf16x8*)&As1[(wm * 4 + mt) * 512 + inoff];
            a2[mt] = *(bf16x8*)&As2[(wm * 4 + mt) * 512 + inoff];
        }
        #pragma unroll
        for (int nt = 0; nt < 2; ++nt) {
            bf16x8 b1 = *(bf16x8*)&Bs1[(wn * 2 + nt) * 512 + inoff];
            bf16x8 b2 = *(bf16x8*)&Bs2[(wn * 2 + nt) * 512 + inoff];
            #pragma unroll
            for (int mt = 0; mt < 4; ++mt) {
                acc1[mt][nt] = __builtin_amdgcn_mfma_f32_16x16x32_bf16(a1[mt], b1, acc1[mt][nt], 0, 0, 0);
                acc2[mt][nt] = __builtin_amdgcn_mfma_f32_16x16x32_bf16(a2[mt], b2, acc2[mt][nt], 0, 0, 0);
            }
        }
        __syncthreads();
    }

    #pragma unroll
    for (int mt = 0; mt < 4; ++mt)
        #pragma unroll
        for (int nt = 0; nt < 2; ++nt) {
            #pragma unroll
            for (int reg = 0; reg < 4; ++reg) {
                int row = row0 + wm * 64 + mt * 16 + fq * 4 + reg;
                int col = col0 + wn * 32 + nt * 16 + fr;
                float v = acc1[mt][nt][reg] * acc2[mt][nt][reg];
                int kbo = col >> 5, kl = col & 31;
                int chunk = row >> 4, rl = row & 15;
                int g = (rl & 7) | (((kl >> 3) & 3) << 3) | ((rl >> 3) << 5);
                fusedt[(size_t)kbo * (144 * 512) + chunk * 512 + g * 8 + (kl & 7)] = f2bf(v);
            }
        }
}

// ---------------------------------------------------------------------------
// K2: same structure; ra/rb f32 row-major out.
// ---------------------------------------------------------------------------
__global__ __launch_bounds__(256, 2)
void k2_dual_mfma(const unsigned short* __restrict__ Ft,
                  const unsigned short* __restrict__ Wfat,
                  const unsigned short* __restrict__ Wfbt,
                  float* __restrict__ ra, float* __restrict__ rb)
{
    __shared__ __align__(16) unsigned short As [128 * 32];
    __shared__ __align__(16) unsigned short Bs1[64 * 32];
    __shared__ __align__(16) unsigned short Bs2[64 * 32];

    const int tid = threadIdx.x;
    const int lane = tid & 63;
    const int w = tid >> 6;
    const int wm = w >> 1, wn = w & 1;
    const int row0 = blockIdx.y * 128;
    const int col0 = blockIdx.x * 64;
    const int chA = row0 >> 4;
    const int chB = col0 >> 4;

    f32x4 acc1[4][2], acc2[4][2];
    #pragma unroll
    for (int mt = 0; mt < 4; ++mt)
        #pragma unroll
        for (int nt = 0; nt < 2; ++nt) { acc1[mt][nt] = (f32x4)(0.f); acc2[mt][nt] = (f32x4)(0.f); }

    const int fr = lane & 15, fq = lane >> 4;
    const int inoff = ((fr & 7) << 3) | (fq << 6) | ((fr >> 3) << 8);

    for (int kb = 0; kb < 64; ++kb) {
        #pragma unroll
        for (int t = 0; t < 2; ++t) {
            int cl = w * 2 + t;
            __builtin_amdgcn_global_load_lds((glb_u32*)(Ft + ((size_t)kb * 144 + chA + cl) * 512 + lane * 8),
                                             (lds_u32*)&As[cl * 512], 16, 0, 0);
        }
        __builtin_amdgcn_global_load_lds((glb_u32*)(Wfat + ((size_t)kb * 128 + chB + w) * 512 + lane * 8),
                                         (lds_u32*)&Bs1[w * 512], 16, 0, 0);
        __builtin_amdgcn_global_load_lds((glb_u32*)(Wfbt + ((size_t)kb * 128 + chB + w) * 512 + lane * 8),
                                         (lds_u32*)&Bs2[w * 512], 16, 0, 0);
        __syncthreads();

        bf16x8 a[4];
        #pragma unroll
        for (int mt = 0; mt < 4; ++mt)
            a[mt] = *(bf16x8*)&As[(wm * 4 + mt) * 512 + inoff];
        #pragma unroll
        for (int nt = 0; nt < 2; ++nt) {
            bf16x8 b1 = *(bf16x8*)&Bs1[(wn * 2 + nt) * 512 + inoff];
            bf16x8 b2 = *(bf16x8*)&Bs2[(wn * 2 + nt) * 512 + inoff];
            #pragma unroll
            for (int mt = 0; mt < 4; ++mt) {
                acc1[mt][nt] = __builtin_amdgcn_mfma_f32_16x16x32_bf16(a[mt], b1, acc1[mt][nt], 0, 0, 0);
                acc2[mt][nt] = __builtin_amdgcn_mfma_f32_16x16x32_bf16(a[mt], b2, acc2[mt][nt], 0, 0, 0);
            }
        }
        __syncthreads();
    }

    #pragma unroll
    for (int mt = 0; mt < 4; ++mt)
        #pragma unroll
        for (int nt = 0; nt < 2; ++nt) {
            int row = row0 + wm * 64 + mt * 16 + fq * 4;
            int col = col0 + wn * 32 + nt * 16 + fr;
            #pragma unroll
            for (int reg = 0; reg < 4; ++reg) {
                size_t o = (size_t)(row + reg) * kD + col;
                ra[o] = acc1[mt][nt][reg];
                rb[o] = acc2[mt][nt][reg];
            }
        }
}

// ---------------------------------------------------------------------------
// K4 v13: B-fragments DIRECT FROM L2 (no Bs LDS, no DMA in the K-loop).
//
// W0s is 2.1 MB -> L2-resident per XCD. In the tiled-permuted layout a
// wave's B-fragment load is exactly one coalesced 1KB chunk, so Bs staging
// was pure overhead: it added 32 KB/step of LDS traffic AND forced the
// per-step barrier to drain vmcnt(0) (the global_load_lds queue). Removing
// it cuts the LDS floor 110->78 KB/step and turns the barrier into a cheap
// lgkmcnt-only sync. L2 B-traffic 2.9 GB over the kernel (~34% agg L2 BW).
// Everything else (N-split 2 blocks/CU, rank-16 box K-step, REL_GEN
// pipeline) is v11, hazard-identical.
// ---------------------------------------------------------------------------
__global__ __launch_bounds__(512, 4)
void k4_scores_mfma(const float* __restrict__ ra, const float* __restrict__ rb,
                    const float* __restrict__ box,
                    const unsigned short* __restrict__ W0s,
                    const float* __restrict__ b0, const float* __restrict__ W1,
                    float* __restrict__ scores)
{
    __shared__ __align__(16) unsigned short RelS[2][128][40]; // 20 KB
    __shared__ __align__(16) float4 Stg4[2][378];             // 12 KB
    __shared__ float scoreS[128];

    const int tid  = threadIdx.x;
    const int lane = tid & 63;
    const int w    = tid >> 6;        // 0..7
    const int wm   = w >> 2;
    const int wn   = w & 3;

    const int work = (blockIdx.x & 7) * 176 + (blockIdx.x >> 3);
    const int colb = work & 1;
    const int wt   = work >> 1;
    const int b    = wt / 11;
    const int tile = wt - b * 11;
    const int p0   = tile * 128;
    const int i0   = p0 / kN;

    const float* raB  = ra  + (size_t)b * kN * kD;
    const float* rbB  = rb  + (size_t)b * kN * kD;
    const float* boxB = box + (size_t)b * kN * 4;

    const bool hasStage = (tid < 336);
    const float* sptr;
    int sdst;
    {
        int s = hasStage ? tid : 335;
        int row = s >> 3, q = s & 7;
        int grow; const float* base;
        if (row < 6) {
            int il = (row < 5) ? row : 4;
            grow = i0 + il; if (grow > kN - 1) grow = kN - 1;
            base = raB;
        } else {
            grow = row - 6;
            base = rbB;
        }
        sptr = base + (size_t)grow * kD + q * 4;
        sdst = row * 9 + q;
    }

    int rowA, cg2, iA, jA, sA, sR;
    {
        rowA = tid >> 2; cg2 = tid & 3;
        int p = p0 + rowA; if (p >= kPairs) p = kPairs - 1;
        iA = p / kN;
        jA = p - iA * kN;
        int ilA = iA - i0;
        sA = ilA * 9 + cg2 * 2;
        sR = (6 + jA) * 9 + cg2 * 2;
    }

    const int fr = lane & 15, fq = lane >> 4;
    const int bco = ((fr & 7) << 3) + ((fr >> 3) << 8) + (fq << 6);
    // per-lane base into W0s for this wave's 4 B-chunks
    const unsigned short* w0base = W0s + (size_t)(colb * 16 + wn * 4) * 512 + bco;

    f32x4 acc[4][4];
    #pragma unroll
    for (int mt = 0; mt < 4; ++mt)
        #pragma unroll
        for (int nt = 0; nt < 4; ++nt)
            acc[mt][nt] = (f32x4)(0.f);

    if (tid < 128) scoreS[tid] = 0.f;

    float4 sreg0;

    #define STAGE_LOAD(k0_) {                                                    \
            if (hasStage) sreg0 = *(const float4*)(sptr + (k0_));                \
        }

    #define STAGE_WRITE(buf_) {                                                  \
            if (hasStage) Stg4[buf_][sdst] = sreg0;                              \
        }

    #define REL_GEN(buf_) {                                                      \
            float4 va0 = Stg4[buf_][sA],     va1 = Stg4[buf_][sA + 1];           \
            float4 vr0 = Stg4[buf_][sR],     vr1 = Stg4[buf_][sR + 1];           \
            unsigned short o[8];                                                 \
            o[0] = f2bf(va0.x * vr0.x); o[1] = f2bf(va0.y * vr0.y);              \
            o[2] = f2bf(va0.z * vr0.z); o[3] = f2bf(va0.w * vr0.w);              \
            o[4] = f2bf(va1.x * vr1.x); o[5] = f2bf(va1.y * vr1.y);              \
            o[6] = f2bf(va1.z * vr1.z); o[7] = f2bf(va1.w * vr1.w);              \
            *(bf16x8*)&RelS[buf_][rowA][cg2 * 8] = *(bf16x8*)o;                  \
        }

    #define REL_GEN_BOX(buf_) {                                                  \
            unsigned short o[8] = {0, 0, 0, 0, 0, 0, 0, 0};                      \
            if (cg2 < 2) {                                                       \
                float4 bj = *(const float4*)(boxB + jA * 4);                     \
                float biu0 = boxB[iA * 4 + cg2 * 2];                             \
                float biu1 = boxB[iA * 4 + cg2 * 2 + 1];                         \
                o[0] = f2bf(biu0 * bj.x); o[1] = f2bf(biu0 * bj.y);              \
                o[2] = f2bf(biu0 * bj.z); o[3] = f2bf(biu0 * bj.w);              \
                o[4] = f2bf(biu1 * bj.x); o[5] = f2bf(biu1 * bj.y);              \
                o[6] = f2bf(biu1 * bj.z); o[7] = f2bf(biu1 * bj.w);              \
            }                                                                    \
            *(bf16x8*)&RelS[buf_][rowA][cg2 * 8] = *(bf16x8*)o;                  \
        }

    STAGE_LOAD(0)
    STAGE_WRITE(0)
    STAGE_LOAD(32)
    __syncthreads();          // Stg[0] visible
    REL_GEN(0)
    STAGE_WRITE(1)

    for (int k = 0; k <= 64; ++k) {
        const int cur = k & 1, nxt = cur ^ 1;
        __syncthreads();      // RelS[cur], Stg[nxt] visible (no DMA to drain)
        // B-fragments straight from L2 (issued first: latency hides under
        // REL_GEN + af reads)
        bf16x8 bfv[4];
        #pragma unroll
        for (int nt = 0; nt < 4; ++nt)
            bfv[nt] = *(const bf16x8*)(w0base + (size_t)k * 16384 + nt * 512);
        if (k < 62) STAGE_LOAD((k + 2) * 32)
        bf16x8 af[4];
        #pragma unroll
        for (int mt = 0; mt < 4; ++mt)
            af[mt] = *(bf16x8*)&RelS[cur][wm * 64 + mt * 16 + fr][fq * 8];
        if (k < 63) REL_GEN(nxt)
        else if (k == 63) REL_GEN_BOX(nxt)
        __builtin_amdgcn_s_setprio(1);
        #pragma unroll
        for (int nt = 0; nt < 4; ++nt)
            #pragma unroll
            for (int mt = 0; mt < 4; ++mt)
                acc[mt][nt] = __builtin_amdgcn_mfma_f32_16x16x32_bf16(af[mt], bfv[nt], acc[mt][nt], 0, 0, 0);
        __builtin_amdgcn_s_setprio(0);
        if (k < 62) STAGE_WRITE(cur)
    }

    float b0v[4], w1v[4];
    #pragma unroll
    for (int nt = 0; nt < 4; ++nt) {
        int col = colb * 256 + wn * 64 + nt * 16 + fr;
        b0v[nt] = b0[col];
        w1v[nt] = W1[col];
    }
    #pragma unroll
    for (int mt = 0; mt < 4; ++mt) {
        #pragma unroll
        for (int reg = 0; reg < 4; ++reg) {
            float p = 0.f;
            #pragma unroll
            for (int nt = 0; nt < 4; ++nt)
                p += w1v[nt] * tanhf(acc[mt][nt][reg] + b0v[nt]);
            p += __shfl_xor(p, 1, 64);
            p += __shfl_xor(p, 2, 64);
            p += __shfl_xor(p, 4, 64);
            p += __shfl_xor(p, 8, 64);
            if (fr == 0)
                atomicAdd(&scoreS[wm * 64 + mt * 16 + fq * 4 + reg], p);
        }
    }
    __syncthreads();
    if (tid < 128 && p0 + tid < kPairs)
        atomicAdd(&scores[(size_t)b * kPairs + p0 + tid], scoreS[tid]);
}

// ---------------------------------------------------------------------------
// K5: softmax over j + abox[bi,:] = sum_j att[bi,j] * box[b,j,:]
// ---------------------------------------------------------------------------
__global__ __launch_bounds__(64)
void k5_softmax(const float* __restrict__ scores, const float* __restrict__ box,
                float* __restrict__ att, float* __restrict__ abox)
{
    const int bi = blockIdx.x;
    const int b  = bi / kN;
    const int tid = threadIdx.x;
    float s = (tid < kN) ? scores[(size_t)bi * kN + tid] : -1e30f;
    float m = s;
    #pragma unroll
    for (int off = 32; off >= 1; off >>= 1)
        m = fmaxf(m, __shfl_xor(m, off, 64));
    float e = (tid < kN) ? expf(s - m) : 0.f;
    float sum = e;
    #pragma unroll
    for (int off = 32; off >= 1; off >>= 1)
        sum += __shfl_xor(sum, off, 64);
    float a = e / sum;
    if (tid < kN) att[(size_t)bi * kN + tid] = a;

    float4 bx = {0.f, 0.f, 0.f, 0.f};
    if (tid < kN) bx = *(const float4*)(box + (size_t)(b * kN + tid) * 4);
    bx.x *= a; bx.y *= a; bx.z *= a; bx.w *= a;
    #pragma unroll
    for (int off = 32; off >= 1; off >>= 1) {
        bx.x += __shfl_xor(bx.x, off, 64);
        bx.y += __shfl_xor(bx.y, off, 64);
        bx.z += __shfl_xor(bx.z, off, 64);
        bx.w += __shfl_xor(bx.w, off, 64);
    }
    if (tid == 0) *(float4*)(abox + (size_t)bi * 4) = bx;
}

// ---------------------------------------------------------------------------
// K6: XCD-chunked swizzle; rank-4 box term; tiled fused read.
// ---------------------------------------------------------------------------
__global__ __launch_bounds__(256)
void k6_output(const float* __restrict__ obj, const unsigned short* __restrict__ fusedt,
               const float* __restrict__ ra, const float* __restrict__ rb,
               const float* __restrict__ att, const float* __restrict__ box,
               const float* __restrict__ abox,
               const float* __restrict__ Wba, const float* __restrict__ Wbb,
               float* __restrict__ out)
{
    __shared__ float attS[kN];
    const int bi = (blockIdx.x & 7) * 288 + (blockIdx.x >> 3);  // XCD swizzle
    const int b = bi / kN;
    const int tid = threadIdx.x;
    if (tid < kN) attS[tid] = att[(size_t)bi * kN + tid];
    __syncthreads();
    const float4 bxi = *(const float4*)(box  + (size_t)bi * 4);
    const float4 axi = *(const float4*)(abox + (size_t)bi * 4);
    const int chunk = bi >> 4, rl = bi & 15;
    for (int d = tid; d < kD; d += 256) {
        float s1 = 0.f;
        #pragma unroll 4
        for (int j = 0; j < kN; ++j)
            s1 = fmaf(attS[j], rb[(size_t)(b * kN + j) * kD + d], s1);
        float bav = bxi.x * Wba[d] + bxi.y * Wba[kD + d]
                  + bxi.z * Wba[2 * kD + d] + bxi.w * Wba[3 * kD + d];
        float s2  = axi.x * Wbb[d] + axi.y * Wbb[kD + d]
                  + axi.z * Wbb[2 * kD + d] + axi.w * Wbb[3 * kD + d];
        size_t o = (size_t)bi * kD + d;
        int kbf = d >> 5, klf = d & 31;
        int g = (rl & 7) | (((klf >> 3) & 3) << 3) | ((rl >> 3) << 5);
        float fv = __uint_as_float(
            (u32)fusedt[(size_t)kbf * (144 * 512) + chunk * 512 + g * 8 + (klf & 7)] << 16);
        out[o] = obj[o] + fv + ra[o] * s1 + bav * s2;
    }
}

// ---------------------------------------------------------------------------
extern "C" void kernel_launch(void* const* d_in, const int* in_sizes, int n_in,
                              void* d_out, int out_size, void* d_ws, size_t ws_size,
                              hipStream_t stream)
{
    const float* q   = (const float*)d_in[0];
    const float* obj = (const float*)d_in[1];
    const float* box = (const float*)d_in[2];
    const float* Wq  = (const float*)d_in[3];
    const float* Wo  = (const float*)d_in[4];
    const float* Wfa = (const float*)d_in[5];
    const float* Wfb = (const float*)d_in[6];
    const float* Wba = (const float*)d_in[7];
    const float* Wbb = (const float*)d_in[8];
    const float* W0  = (const float*)d_in[9];
    const float* b0v = (const float*)d_in[10];
    const float* W1  = (const float*)d_in[11];
    float* out = (float*)d_out;

    const size_t nBD = (size_t)kBN * kD;
    float* ws = (float*)d_ws;
    size_t off = 0;
    float* ra     = ws + off; off += nBD;
    float* rb     = ws + off; off += nBD;
    float* scores = ws + off; off += (size_t)kBN * kN;
    float* att    = ws + off; off += (size_t)kBN * kN;
    float* abox   = ws + off; off += (size_t)kBN * 4;
    float* Gpart  = ws + off; off += (size_t)16 * 16 * kDatt;

    unsigned short* us = (unsigned short*)(ws + off);
    size_t uoff = 0;
    unsigned short* W0s    = us + uoff; uoff += (size_t)65 * 16384;
    unsigned short* qt     = us + uoff; uoff += nBD;
    unsigned short* objt   = us + uoff; uoff += nBD;
    unsigned short* fusedt = us + uoff; uoff += nBD;
    unsigned short* Wqt    = us + uoff; uoff += (size_t)kD * kD;
    unsigned short* Wot    = us + uoff; uoff += (size_t)kD * kD;
    unsigned short* Wfat   = us + uoff; uoff += (size_t)kD * kD;
    unsigned short* Wfbt   = us + uoff; uoff += (size_t)kD * kD;

    kcvt2<<<dim3(kBN * (kD / 4) / 256, 2), 256, 0, stream>>>(q, obj, qt, objt);
    ktrp5<<<dim3(32, 32, 5), 256, 0, stream>>>(Wq, Wo, Wfa, Wfb, W0,
                                               Wqt, Wot, Wfat, Wfbt, W0s);
    kgbox<<<dim3(8, 16), 256, 0, stream>>>(Wba, Wbb, W0, Gpart);
    krepack_g<<<dim3(32), 64, 0, stream>>>(Gpart, W0s);
    kzero<<<dim3((kBN * kN + 255) / 256), 256, 0, stream>>>(scores, kBN * kN);

    k1_dual_mfma<<<dim3(kD / 64, kBN / 128), 256, 0, stream>>>(qt, Wqt, objt, Wot, fusedt);
    k2_dual_mfma<<<dim3(kD / 64, kBN / 128), 256, 0, stream>>>(fusedt, Wfat, Wfbt, ra, rb);

    k4_scores_mfma<<<dim3(kB * 11 * 2), 512, 0, stream>>>(ra, rb, box, W0s, b0v, W1, scores);
    k5_softmax<<<kBN, 64, 0, stream>>>(scores, box, att, abox);
    k6_output<<<kBN, 256, 0, stream>>>(obj, fusedt, ra, rb, att, box, abox, Wba, Wbb, out);
}